// Round 1
// baseline (701.409 us; speedup 1.0000x reference)
//
#include <hip/hip_runtime.h>
#include <math.h>

// Problem constants (from reference): B=8, L=512, HID=256, LAT=256, EXP=2 -> INNER=512, NL=3
// M = B*L = 4096 token rows.

__device__ __forceinline__ void wave_reduce2(float& a, float& b) {
#pragma unroll
  for (int off = 32; off > 0; off >>= 1) {
    a += __shfl_xor(a, off, 64);
    b += __shfl_xor(b, off, 64);
  }
}

__device__ __forceinline__ float wave_reduce1(float a) {
#pragma unroll
  for (int off = 32; off > 0; off >>= 1) a += __shfl_xor(a, off, 64);
  return a;
}

// ---------------------------------------------------------------------------
// GEMM1: h = LayerNorm(x @ W)  ; x:[4096,256]  W:[256,256]  out:[4096,256]
// Block: 256 thr = 4 waves; each wave owns 8 rows (full 256-col rows).
// ---------------------------------------------------------------------------
__global__ __launch_bounds__(256) void k_gemm_ln(
    const float* __restrict__ A, const float* __restrict__ W,
    const float* __restrict__ gam, const float* __restrict__ bet,
    float* __restrict__ out) {
  constexpr int R = 32, RS = 8, K = 256;
  __shared__ float sA[R][K];  // 32 KB
  const int tid = threadIdx.x;
  const int row0 = blockIdx.x * R;
  const float4* A4 = (const float4*)(A + (size_t)row0 * K);
  float4* sA4 = (float4*)&sA[0][0];
#pragma unroll
  for (int i = 0; i < (R * K / 4) / 256; ++i) sA4[tid + i * 256] = A4[tid + i * 256];
  __syncthreads();
  const int g = tid >> 6;       // wave id = row group
  const int lane = tid & 63;
  const int c0 = lane * 4;
  float acc[RS][4];
#pragma unroll
  for (int r = 0; r < RS; ++r) acc[r][0] = acc[r][1] = acc[r][2] = acc[r][3] = 0.f;
  for (int k = 0; k < K; k += 4) {
    float4 w0 = *(const float4*)&W[(size_t)(k + 0) * 256 + c0];
    float4 w1 = *(const float4*)&W[(size_t)(k + 1) * 256 + c0];
    float4 w2 = *(const float4*)&W[(size_t)(k + 2) * 256 + c0];
    float4 w3 = *(const float4*)&W[(size_t)(k + 3) * 256 + c0];
#pragma unroll
    for (int r = 0; r < RS; ++r) {
      float4 a = *(const float4*)&sA[g * RS + r][k];  // wave-uniform -> broadcast
      acc[r][0] += a.x * w0.x + a.y * w1.x + a.z * w2.x + a.w * w3.x;
      acc[r][1] += a.x * w0.y + a.y * w1.y + a.z * w2.y + a.w * w3.y;
      acc[r][2] += a.x * w0.z + a.y * w1.z + a.z * w2.z + a.w * w3.z;
      acc[r][3] += a.x * w0.w + a.y * w1.w + a.z * w2.w + a.w * w3.w;
    }
  }
  float4 gm = *(const float4*)&gam[c0];
  float4 bt = *(const float4*)&bet[c0];
#pragma unroll
  for (int r = 0; r < RS; ++r) {
    float s = acc[r][0] + acc[r][1] + acc[r][2] + acc[r][3];
    float sq = acc[r][0] * acc[r][0] + acc[r][1] * acc[r][1] +
               acc[r][2] * acc[r][2] + acc[r][3] * acc[r][3];
    wave_reduce2(s, sq);
    float mu = s * (1.f / 256.f);
    float rstd = rsqrtf(sq * (1.f / 256.f) - mu * mu + 1e-5f);
    int row = row0 + g * RS + r;
    float4 o;
    o.x = (acc[r][0] - mu) * rstd * gm.x + bt.x;
    o.y = (acc[r][1] - mu) * rstd * gm.y + bt.y;
    o.z = (acc[r][2] - mu) * rstd * gm.z + bt.z;
    o.w = (acc[r][3] - mu) * rstd * gm.w + bt.w;
    *(float4*)&out[(size_t)row * 256 + c0] = o;
  }
}

// ---------------------------------------------------------------------------
// Row LayerNorm: out = LN(in) ; rows of width 256, one wave per row.
// ---------------------------------------------------------------------------
__global__ __launch_bounds__(256) void k_ln_rows(
    const float* __restrict__ in, const float* __restrict__ g,
    const float* __restrict__ b, float* __restrict__ out) {
  const int gid = blockIdx.x * 256 + threadIdx.x;
  const int row = gid >> 6;
  const int lane = gid & 63;
  const int c0 = lane * 4;
  float4 v = *(const float4*)&in[(size_t)row * 256 + c0];
  float s = v.x + v.y + v.z + v.w;
  float sq = v.x * v.x + v.y * v.y + v.z * v.z + v.w * v.w;
  wave_reduce2(s, sq);
  float mu = s * (1.f / 256.f);
  float rstd = rsqrtf(sq * (1.f / 256.f) - mu * mu + 1e-5f);
  float4 gg = *(const float4*)&g[c0];
  float4 bb = *(const float4*)&b[c0];
  float4 o;
  o.x = (v.x - mu) * rstd * gg.x + bb.x;
  o.y = (v.y - mu) * rstd * gg.y + bb.y;
  o.z = (v.z - mu) * rstd * gg.z + bb.z;
  o.w = (v.w - mu) * rstd * gg.w + bb.w;
  *(float4*)&out[(size_t)row * 256 + c0] = o;
}

// ---------------------------------------------------------------------------
// GEMM2: xp = hn @ in_w ; hn:[4096,256] in_w:[256,1024] xp:[4096,1024]
// ---------------------------------------------------------------------------
__global__ __launch_bounds__(256) void k_gemm_wide(
    const float* __restrict__ A, const float* __restrict__ W,
    float* __restrict__ out) {
  constexpr int R = 16, K = 256, N = 1024;
  __shared__ float sA[R][K];  // 16 KB
  const int tid = threadIdx.x;
  const int row0 = blockIdx.x * R;
  const float4* A4 = (const float4*)(A + (size_t)row0 * K);
  float4* sA4 = (float4*)&sA[0][0];
#pragma unroll
  for (int i = 0; i < (R * K / 4) / 256; ++i) sA4[tid + i * 256] = A4[tid + i * 256];
  __syncthreads();
  const int c0 = tid * 4;
  float acc[R][4];
#pragma unroll
  for (int r = 0; r < R; ++r) acc[r][0] = acc[r][1] = acc[r][2] = acc[r][3] = 0.f;
  for (int k = 0; k < K; k += 4) {
    float4 w0 = *(const float4*)&W[(size_t)(k + 0) * N + c0];
    float4 w1 = *(const float4*)&W[(size_t)(k + 1) * N + c0];
    float4 w2 = *(const float4*)&W[(size_t)(k + 2) * N + c0];
    float4 w3 = *(const float4*)&W[(size_t)(k + 3) * N + c0];
#pragma unroll
    for (int r = 0; r < R; ++r) {
      float4 a = *(const float4*)&sA[r][k];  // block-uniform -> broadcast
      acc[r][0] += a.x * w0.x + a.y * w1.x + a.z * w2.x + a.w * w3.x;
      acc[r][1] += a.x * w0.y + a.y * w1.y + a.z * w2.y + a.w * w3.y;
      acc[r][2] += a.x * w0.z + a.y * w1.z + a.z * w2.z + a.w * w3.z;
      acc[r][3] += a.x * w0.w + a.y * w1.w + a.z * w2.w + a.w * w3.w;
    }
  }
#pragma unroll
  for (int r = 0; r < R; ++r) {
    float4 o = {acc[r][0], acc[r][1], acc[r][2], acc[r][3]};
    *(float4*)&out[(size_t)(row0 + r) * N + c0] = o;
  }
}

// ---------------------------------------------------------------------------
// Conv3 + decay scan + gate: y[b,t,d] = s[t]*sigmoid(g) where
//   s[t] = sig(decay)*s[t-1] + (1-sig(decay))*scale*conv3(u)[t]
// One thread per (b, d) channel; coalesced across d.
// ---------------------------------------------------------------------------
__global__ __launch_bounds__(256) void k_scan(
    const float* __restrict__ xp, const float* __restrict__ cw,
    const float* __restrict__ decay, const float* __restrict__ scl,
    float* __restrict__ y) {
  const int id = blockIdx.x * 256 + threadIdx.x;  // 0..4095
  const int b = id >> 9;
  const int d = id & 511;
  const float dec = decay[d];
  const float dsig = 1.f / (1.f + expf(-dec));
  const float coef = (1.f - dsig) * scl[d];
  const float cw0 = cw[d * 3 + 0], cw1 = cw[d * 3 + 1], cw2 = cw[d * 3 + 2];
  const float* urow = xp + (size_t)b * 512 * 1024 + d;
  const float* grow = urow + 512;
  float* yrow = y + (size_t)b * 512 * 512 + d;
  float um1 = 0.f, um2 = 0.f, s = 0.f;
  for (int t = 0; t < 512; ++t) {
    float u = urow[(size_t)t * 1024];
    float gv = grow[(size_t)t * 1024];
    float uc = cw0 * um2 + cw1 * um1 + cw2 * u;
    s = dsig * s + coef * uc;
    float sig = 1.f / (1.f + expf(-gv));
    yrow[(size_t)t * 512] = s * sig;
    um2 = um1;
    um1 = u;
  }
}

// ---------------------------------------------------------------------------
// GEMM3 + RMSNorm + residual: h += RMSNorm(y @ out_w) * rms_w
// y:[4096,512] out_w:[512,256]
// ---------------------------------------------------------------------------
__global__ __launch_bounds__(256) void k_gemm_rms_res(
    const float* __restrict__ A, const float* __restrict__ W,
    const float* __restrict__ rw, float* __restrict__ h) {
  constexpr int R = 16, RS = 4, K = 512;
  __shared__ float sA[R][K];  // 32 KB
  const int tid = threadIdx.x;
  const int row0 = blockIdx.x * R;
  const float4* A4 = (const float4*)(A + (size_t)row0 * K);
  float4* sA4 = (float4*)&sA[0][0];
#pragma unroll
  for (int i = 0; i < (R * K / 4) / 256; ++i) sA4[tid + i * 256] = A4[tid + i * 256];
  __syncthreads();
  const int g = tid >> 6;
  const int lane = tid & 63;
  const int c0 = lane * 4;
  float acc[RS][4];
#pragma unroll
  for (int r = 0; r < RS; ++r) acc[r][0] = acc[r][1] = acc[r][2] = acc[r][3] = 0.f;
  for (int k = 0; k < K; k += 4) {
    float4 w0 = *(const float4*)&W[(size_t)(k + 0) * 256 + c0];
    float4 w1 = *(const float4*)&W[(size_t)(k + 1) * 256 + c0];
    float4 w2 = *(const float4*)&W[(size_t)(k + 2) * 256 + c0];
    float4 w3 = *(const float4*)&W[(size_t)(k + 3) * 256 + c0];
#pragma unroll
    for (int r = 0; r < RS; ++r) {
      float4 a = *(const float4*)&sA[g * RS + r][k];
      acc[r][0] += a.x * w0.x + a.y * w1.x + a.z * w2.x + a.w * w3.x;
      acc[r][1] += a.x * w0.y + a.y * w1.y + a.z * w2.y + a.w * w3.y;
      acc[r][2] += a.x * w0.z + a.y * w1.z + a.z * w2.z + a.w * w3.z;
      acc[r][3] += a.x * w0.w + a.y * w1.w + a.z * w2.w + a.w * w3.w;
    }
  }
  float4 rr = *(const float4*)&rw[c0];
#pragma unroll
  for (int r = 0; r < RS; ++r) {
    float sq = acc[r][0] * acc[r][0] + acc[r][1] * acc[r][1] +
               acc[r][2] * acc[r][2] + acc[r][3] * acc[r][3];
    sq = wave_reduce1(sq);
    float rstd = rsqrtf(sq * (1.f / 256.f) + 1e-6f);
    int row = row0 + g * RS + r;
    float4 ho = *(const float4*)&h[(size_t)row * 256 + c0];
    float4 o;
    o.x = ho.x + acc[r][0] * rstd * rr.x;
    o.y = ho.y + acc[r][1] * rstd * rr.y;
    o.z = ho.z + acc[r][2] * rstd * rr.z;
    o.w = ho.w + acc[r][3] * rstd * rr.w;
    *(float4*)&h[(size_t)row * 256 + c0] = o;
  }
}

// ---------------------------------------------------------------------------
// Pool: pooled[b,c] = mean_t(h)*0.5 + h[b,L-1,c]*0.5
// ---------------------------------------------------------------------------
__global__ __launch_bounds__(256) void k_pool(const float* __restrict__ h,
                                              float* __restrict__ pooled) {
  const int b = blockIdx.x;
  const int c = threadIdx.x;
  float s = 0.f;
  for (int t = 0; t < 512; ++t) s += h[((size_t)b * 512 + t) * 256 + c];
  float last = h[((size_t)b * 512 + 511) * 256 + c];
  pooled[b * 256 + c] = s * (0.5f / 512.f) + 0.5f * last;
}

// ---------------------------------------------------------------------------
// Head: z = GELU(LN(pooled@w1+b1)); out = z@w2+b2 ; one block per batch row.
// ---------------------------------------------------------------------------
__global__ __launch_bounds__(256) void k_head(
    const float* __restrict__ pooled, const float* __restrict__ w1,
    const float* __restrict__ b1, const float* __restrict__ lng,
    const float* __restrict__ lnb, const float* __restrict__ w2,
    const float* __restrict__ b2, float* __restrict__ out) {
  const int b = blockIdx.x;
  const int t = threadIdx.x;
  __shared__ float sp[256];
  __shared__ float sz[256];
  __shared__ float red[8];
  sp[t] = pooled[b * 256 + t];
  __syncthreads();
  float acc = b1[t];
  for (int k = 0; k < 256; ++k) acc += sp[k] * w1[(size_t)k * 256 + t];
  float s = acc, sq = acc * acc;
  wave_reduce2(s, sq);
  const int lane = t & 63, w = t >> 6;
  if (lane == 0) {
    red[w] = s;
    red[4 + w] = sq;
  }
  __syncthreads();
  float S = red[0] + red[1] + red[2] + red[3];
  float SQ = red[4] + red[5] + red[6] + red[7];
  float mu = S * (1.f / 256.f);
  float rstd = rsqrtf(SQ * (1.f / 256.f) - mu * mu + 1e-5f);
  float z = (acc - mu) * rstd * lng[t] + lnb[t];
  z = 0.5f * z * (1.f + erff(z * 0.70710678118654752f));
  sz[t] = z;
  __syncthreads();
#pragma unroll
  for (int j = 0; j < 3; ++j) {
    int c = t + j * 256;
    float a = b2[c];
    for (int k = 0; k < 256; ++k) a += sz[k] * w2[(size_t)k * 768 + c];
    out[(size_t)b * 768 + c] = a;
  }
}

// ---------------------------------------------------------------------------
extern "C" void kernel_launch(void* const* d_in, const int* in_sizes, int n_in,
                              void* d_out, int out_size, void* d_ws, size_t ws_size,
                              hipStream_t stream) {
  const float* x = (const float*)d_in[0];
  const float* in_proj_w = (const float*)d_in[1];
  const float* in_ln_g = (const float*)d_in[2];
  const float* in_ln_b = (const float*)d_in[3];
  const float* norms_g = (const float*)d_in[4];
  const float* norms_b = (const float*)d_in[5];
  const float* blk_in_w = (const float*)d_in[6];
  const float* blk_conv_w = (const float*)d_in[7];
  const float* blk_decay = (const float*)d_in[8];
  const float* blk_scale = (const float*)d_in[9];
  const float* blk_out_w = (const float*)d_in[10];
  const float* blk_rms_w = (const float*)d_in[11];
  const float* head_w1 = (const float*)d_in[12];
  const float* head_b1 = (const float*)d_in[13];
  const float* head_ln_g = (const float*)d_in[14];
  const float* head_ln_b = (const float*)d_in[15];
  const float* head_w2 = (const float*)d_in[16];
  const float* head_b2 = (const float*)d_in[17];

  float* ws = (float*)d_ws;
  float* h = ws;                    // [4096,256]  1,048,576 f
  float* hn = ws + 1048576;         // [4096,256]  1,048,576 f
  float* xp = ws + 2097152;         // [4096,1024] 4,194,304 f
  float* y = ws + 6291456;          // [4096,512]  2,097,152 f
  float* pooled = ws + 8388608;     // [8,256]
  float* out = (float*)d_out;

  k_gemm_ln<<<128, 256, 0, stream>>>(x, in_proj_w, in_ln_g, in_ln_b, h);
  for (int i = 0; i < 3; ++i) {
    k_ln_rows<<<1024, 256, 0, stream>>>(h, norms_g + i * 256, norms_b + i * 256, hn);
    k_gemm_wide<<<256, 256, 0, stream>>>(hn, blk_in_w + (size_t)i * 262144, xp);
    k_scan<<<16, 256, 0, stream>>>(xp, blk_conv_w + i * 1536, blk_decay + i * 512,
                                   blk_scale + i * 512, y);
    k_gemm_rms_res<<<256, 256, 0, stream>>>(y, blk_out_w + (size_t)i * 131072,
                                            blk_rms_w + i * 256, h);
  }
  k_pool<<<8, 256, 0, stream>>>(h, pooled);
  k_head<<<8, 256, 0, stream>>>(pooled, head_w1, head_b1, head_ln_g, head_ln_b,
                                head_w2, head_b2, out);
}

// Round 2
// 223.479 us; speedup vs baseline: 3.1386x; 3.1386x over previous
//
#include <hip/hip_runtime.h>
#include <math.h>

// B=8, L=512, HID=256, LAT=256, INNER=512, NL=3, M=B*L=4096

typedef __attribute__((ext_vector_type(8))) __bf16 bf16x8;
typedef __attribute__((ext_vector_type(4))) float f32x4;

__device__ __forceinline__ unsigned short f2b(float f) {
  unsigned int x = __float_as_uint(f);
  unsigned int r = (x + 0x7fffu + ((x >> 16) & 1u)) >> 16;  // RNE
  return (unsigned short)r;
}
__device__ __forceinline__ float b2f(unsigned short u) {
  return __uint_as_float(((unsigned int)u) << 16);
}

__device__ __forceinline__ void wave_reduce2(float& a, float& b) {
#pragma unroll
  for (int off = 32; off > 0; off >>= 1) {
    a += __shfl_xor(a, off, 64);
    b += __shfl_xor(b, off, 64);
  }
}
__device__ __forceinline__ float wave_reduce1(float a) {
#pragma unroll
  for (int off = 32; off > 0; off >>= 1) a += __shfl_xor(a, off, 64);
  return a;
}

#define GLD16(gsrc, ldst)                                              \
  __builtin_amdgcn_global_load_lds(                                    \
      (const __attribute__((address_space(1))) void*)(gsrc),           \
      (__attribute__((address_space(3))) void*)(ldst), 16, 0, 0)

// ---------------------------------------------------------------------------
// Weight prep: transpose fp32 [R][C] -> bf16 [C][R] for all GEMM weights.
// z=0: in_proj_w 256x256 ; z=1..3: blk_in_w[i] 256x1024 ; z=4..6: blk_out_w[i] 512x256
// ---------------------------------------------------------------------------
__global__ __launch_bounds__(256) void k_prep_w(
    const float* __restrict__ inproj, const float* __restrict__ binw,
    const float* __restrict__ boutw, unsigned short* __restrict__ inwT,
    unsigned short* __restrict__ binwT, unsigned short* __restrict__ boutwT) {
  __shared__ float t[32][33];
  const int z = blockIdx.z;
  const float* src;
  unsigned short* dst;
  int R, Cc;
  if (z == 0) {
    src = inproj; dst = inwT; R = 256; Cc = 256;
  } else if (z <= 3) {
    src = binw + (size_t)(z - 1) * 256 * 1024;
    dst = binwT + (size_t)(z - 1) * 1024 * 256;
    R = 256; Cc = 1024;
  } else {
    src = boutw + (size_t)(z - 4) * 512 * 256;
    dst = boutwT + (size_t)(z - 4) * 256 * 512;
    R = 512; Cc = 256;
  }
  const int bx = blockIdx.x, by = blockIdx.y;
  if (bx * 32 >= Cc || by * 32 >= R) return;
  const int tx = threadIdx.x & 31, ty = threadIdx.x >> 5;  // 32 x 8
#pragma unroll
  for (int j = 0; j < 4; ++j)
    t[ty + j * 8][tx] = src[(size_t)(by * 32 + ty + j * 8) * Cc + bx * 32 + tx];
  __syncthreads();
#pragma unroll
  for (int j = 0; j < 4; ++j)
    dst[(size_t)(bx * 32 + ty + j * 8) * R + by * 32 + tx] = f2b(t[tx][ty + j * 8]);
}

// ---------------------------------------------------------------------------
// Cast x fp32 -> bf16 (4 elems/thread)
// ---------------------------------------------------------------------------
__global__ __launch_bounds__(256) void k_cast(const float* __restrict__ in,
                                              unsigned short* __restrict__ out) {
  const int i = blockIdx.x * 256 + threadIdx.x;
  float4 v = ((const float4*)in)[i];
  ushort4 o;
  o.x = f2b(v.x); o.y = f2b(v.y); o.z = f2b(v.z); o.w = f2b(v.w);
  ((ushort4*)out)[i] = o;
}

// ---------------------------------------------------------------------------
// MFMA GEMM: C[M][ldc] = A[M][KTOT] (bf16) x Bt[N][KTOT]^T (bf16)
// 256 thr = 4 waves arranged 2x2; per wave (BM/2)x(BN/2); 16x16x32 fragments.
// Consistent A/B lane->k mapping: k = 8*(lane>>4)+e (bijective over 32).
// C/D layout (verified m89): col = lane&15, row = (lane>>4)*4 + reg.
// ---------------------------------------------------------------------------
template <int BM, int BN, int KTOT, bool OBF16>
__global__ __launch_bounds__(256) void k_mfma_gemm(
    const unsigned short* __restrict__ A, const unsigned short* __restrict__ Bt,
    void* __restrict__ C, int ldc) {
  constexpr int WTM = BM / 2, WTN = BN / 2;
  constexpr int FM = WTM / 16, FN = WTN / 16;
  __shared__ unsigned short sA[BM * 32];
  __shared__ unsigned short sB[BN * 32];
  const int tid = threadIdx.x;
  const int lane = tid & 63;
  const int wave = tid >> 6;
  const int wr = wave >> 1, wc = wave & 1;
  const int bm0 = blockIdx.x * BM, bn0 = blockIdx.y * BN;
  const int fr = lane & 15, fg = lane >> 4;
  f32x4 acc[FM][FN] = {};
  for (int kt = 0; kt < KTOT; kt += 32) {
    __syncthreads();  // previous iteration's LDS reads done
    constexpr int CA = (BM * 4) / 256;
#pragma unroll
    for (int j = 0; j < CA; ++j) {
      int idx = tid + j * 256;
      int row = idx >> 2, slot = idx & 3;
      const unsigned short* src = A + (size_t)(bm0 + row) * KTOT + kt + slot * 8;
      GLD16(src, &sA[idx * 8]);
    }
    constexpr int CB = (BN * 4) / 256;
#pragma unroll
    for (int j = 0; j < CB; ++j) {
      int idx = tid + j * 256;
      int row = idx >> 2, slot = idx & 3;
      const unsigned short* src = Bt + (size_t)(bn0 + row) * KTOT + kt + slot * 8;
      GLD16(src, &sB[idx * 8]);
    }
    __syncthreads();  // vmcnt(0) drained by compiler before barrier
    bf16x8 af[FM], bf[FN];
#pragma unroll
    for (int m = 0; m < FM; ++m)
      af[m] = *(const bf16x8*)&sA[(wr * WTM + m * 16 + fr) * 32 + fg * 8];
#pragma unroll
    for (int n = 0; n < FN; ++n)
      bf[n] = *(const bf16x8*)&sB[(wc * WTN + n * 16 + fr) * 32 + fg * 8];
#pragma unroll
    for (int m = 0; m < FM; ++m)
#pragma unroll
      for (int n = 0; n < FN; ++n)
        acc[m][n] =
            __builtin_amdgcn_mfma_f32_16x16x32_bf16(af[m], bf[n], acc[m][n], 0, 0, 0);
  }
#pragma unroll
  for (int m = 0; m < FM; ++m)
#pragma unroll
    for (int n = 0; n < FN; ++n)
#pragma unroll
      for (int j = 0; j < 4; ++j) {
        int row = bm0 + wr * WTM + m * 16 + fg * 4 + j;
        int col = bn0 + wc * WTN + n * 16 + fr;
        float v = acc[m][n][j];
        if (OBF16)
          ((unsigned short*)C)[(size_t)row * ldc + col] = f2b(v);
        else
          ((float*)C)[(size_t)row * ldc + col] = v;
      }
}

// ---------------------------------------------------------------------------
// Row LayerNorm over width 256, one wave per row; out fp32 or bf16.
// ---------------------------------------------------------------------------
template <bool OBF16>
__global__ __launch_bounds__(256) void k_ln(const float* __restrict__ in,
                                            const float* __restrict__ g,
                                            const float* __restrict__ b,
                                            void* __restrict__ out) {
  const int gid = blockIdx.x * 256 + threadIdx.x;
  const int row = gid >> 6, lane = gid & 63, c0 = lane * 4;
  float4 v = *(const float4*)&in[(size_t)row * 256 + c0];
  float s = v.x + v.y + v.z + v.w;
  float sq = v.x * v.x + v.y * v.y + v.z * v.z + v.w * v.w;
  wave_reduce2(s, sq);
  float mu = s * (1.f / 256.f);
  float rstd = rsqrtf(sq * (1.f / 256.f) - mu * mu + 1e-5f);
  float4 gg = *(const float4*)&g[c0];
  float4 bb = *(const float4*)&b[c0];
  float4 o;
  o.x = (v.x - mu) * rstd * gg.x + bb.x;
  o.y = (v.y - mu) * rstd * gg.y + bb.y;
  o.z = (v.z - mu) * rstd * gg.z + bb.z;
  o.w = (v.w - mu) * rstd * gg.w + bb.w;
  if (OBF16) {
    ushort4 u;
    u.x = f2b(o.x); u.y = f2b(o.y); u.z = f2b(o.z); u.w = f2b(o.w);
    *(ushort4*)&((unsigned short*)out)[(size_t)row * 256 + c0] = u;
  } else {
    *(float4*)&((float*)out)[(size_t)row * 256 + c0] = o;
  }
}

// ---------------------------------------------------------------------------
// Chunked parallel scan: s[t] = a*s[t-1] + coef*conv3(u)[t]; y = s*sigmoid(g)
// Block = (b, 32-d tile); 256 thr = 32 d x 8 chunks of 64 t.
// Pass1: local scan (zero init) -> chunk-end values; LDS carry resolve via a^64;
// Pass2: re-scan with true init, apply gate, store bf16.
// ---------------------------------------------------------------------------
__global__ __launch_bounds__(256) void k_scan2(
    const unsigned short* __restrict__ xp, const float* __restrict__ cw,
    const float* __restrict__ decay, const float* __restrict__ scl,
    unsigned short* __restrict__ y) {
  const int b = blockIdx.y;
  const int d0 = blockIdx.x * 32;
  const int ds = threadIdx.x & 31;
  const int ch = threadIdx.x >> 5;
  const int d = d0 + ds;
  const float a = 1.f / (1.f + expf(-decay[d]));
  const float coef = (1.f - a) * scl[d];
  const float cw0 = cw[d * 3], cw1 = cw[d * 3 + 1], cw2 = cw[d * 3 + 2];
  const int T0 = ch * 64;
  const unsigned short* up = xp + ((size_t)b * 512) * 1024 + d;
  __shared__ float lend[8][32];
  __shared__ float carry[8][32];
  float um1 = T0 >= 1 ? b2f(up[(size_t)(T0 - 1) * 1024]) : 0.f;
  float um2 = T0 >= 2 ? b2f(up[(size_t)(T0 - 2) * 1024]) : 0.f;
  float s = 0.f;
  for (int t = T0; t < T0 + 64; ++t) {
    float u = b2f(up[(size_t)t * 1024]);
    float uc = cw0 * um2 + cw1 * um1 + cw2 * u;
    s = a * s + coef * uc;
    um2 = um1;
    um1 = u;
  }
  lend[ch][ds] = s;
  __syncthreads();
  if (threadIdx.x < 32) {
    float aa = 1.f / (1.f + expf(-decay[d0 + threadIdx.x]));
    float a64 = aa * aa;            // a^2
    a64 = a64 * a64;                // a^4
    a64 = a64 * a64;                // a^8
    a64 = a64 * a64;                // a^16
    a64 = a64 * a64;                // a^32
    a64 = a64 * a64;                // a^64
    float c = 0.f;
#pragma unroll
    for (int j = 0; j < 8; ++j) {
      carry[j][threadIdx.x] = c;
      c = lend[j][threadIdx.x] + a64 * c;
    }
  }
  __syncthreads();
  s = carry[ch][ds];
  um1 = T0 >= 1 ? b2f(up[(size_t)(T0 - 1) * 1024]) : 0.f;
  um2 = T0 >= 2 ? b2f(up[(size_t)(T0 - 2) * 1024]) : 0.f;
  unsigned short* yp = y + ((size_t)b * 512) * 512 + d;
  for (int t = T0; t < T0 + 64; ++t) {
    float u = b2f(up[(size_t)t * 1024]);
    float gv = b2f(up[(size_t)t * 1024 + 512]);
    float uc = cw0 * um2 + cw1 * um1 + cw2 * u;
    s = a * s + coef * uc;
    float sig = 1.f / (1.f + __expf(-gv));
    yp[(size_t)t * 512] = f2b(s * sig);
    um2 = um1;
    um1 = u;
  }
}

// ---------------------------------------------------------------------------
// h += RMSNorm(G) * rw ; one wave per 256-wide row.
// ---------------------------------------------------------------------------
__global__ __launch_bounds__(256) void k_rms_res(const float* __restrict__ G,
                                                 const float* __restrict__ rw,
                                                 float* __restrict__ h) {
  const int gid = blockIdx.x * 256 + threadIdx.x;
  const int row = gid >> 6, lane = gid & 63, c0 = lane * 4;
  float4 v = *(const float4*)&G[(size_t)row * 256 + c0];
  float sq = v.x * v.x + v.y * v.y + v.z * v.z + v.w * v.w;
  sq = wave_reduce1(sq);
  float rstd = rsqrtf(sq * (1.f / 256.f) + 1e-6f);
  float4 rr = *(const float4*)&rw[c0];
  float4 hh = *(const float4*)&h[(size_t)row * 256 + c0];
  hh.x += v.x * rstd * rr.x;
  hh.y += v.y * rstd * rr.y;
  hh.z += v.z * rstd * rr.z;
  hh.w += v.w * rstd * rr.w;
  *(float4*)&h[(size_t)row * 256 + c0] = hh;
}

// ---------------------------------------------------------------------------
__global__ __launch_bounds__(256) void k_pool(const float* __restrict__ h,
                                              float* __restrict__ pooled) {
  const int b = blockIdx.x;
  const int c = threadIdx.x;
  float s = 0.f;
#pragma unroll 4
  for (int t = 0; t < 512; ++t) s += h[((size_t)b * 512 + t) * 256 + c];
  float last = h[((size_t)b * 512 + 511) * 256 + c];
  pooled[b * 256 + c] = s * (0.5f / 512.f) + 0.5f * last;
}

__global__ __launch_bounds__(256) void k_head(
    const float* __restrict__ pooled, const float* __restrict__ w1,
    const float* __restrict__ b1, const float* __restrict__ lng,
    const float* __restrict__ lnb, const float* __restrict__ w2,
    const float* __restrict__ b2, float* __restrict__ out) {
  const int b = blockIdx.x;
  const int t = threadIdx.x;
  __shared__ float sp[256];
  __shared__ float sz[256];
  __shared__ float red[8];
  sp[t] = pooled[b * 256 + t];
  __syncthreads();
  float acc = b1[t];
#pragma unroll 8
  for (int k = 0; k < 256; ++k) acc += sp[k] * w1[(size_t)k * 256 + t];
  float s = acc, sq = acc * acc;
  wave_reduce2(s, sq);
  const int lane = t & 63, w = t >> 6;
  if (lane == 0) {
    red[w] = s;
    red[4 + w] = sq;
  }
  __syncthreads();
  float S = red[0] + red[1] + red[2] + red[3];
  float SQ = red[4] + red[5] + red[6] + red[7];
  float mu = S * (1.f / 256.f);
  float rstd = rsqrtf(SQ * (1.f / 256.f) - mu * mu + 1e-5f);
  float z = (acc - mu) * rstd * lng[t] + lnb[t];
  z = 0.5f * z * (1.f + erff(z * 0.70710678118654752f));
  sz[t] = z;
  __syncthreads();
#pragma unroll
  for (int j = 0; j < 3; ++j) {
    int c = t + j * 256;
    float a = b2[c];
#pragma unroll 8
    for (int k = 0; k < 256; ++k) a += sz[k] * w2[(size_t)k * 768 + c];
    out[(size_t)b * 768 + c] = a;
  }
}

// ---------------------------------------------------------------------------
extern "C" void kernel_launch(void* const* d_in, const int* in_sizes, int n_in,
                              void* d_out, int out_size, void* d_ws, size_t ws_size,
                              hipStream_t stream) {
  const float* x = (const float*)d_in[0];
  const float* in_proj_w = (const float*)d_in[1];
  const float* in_ln_g = (const float*)d_in[2];
  const float* in_ln_b = (const float*)d_in[3];
  const float* norms_g = (const float*)d_in[4];
  const float* norms_b = (const float*)d_in[5];
  const float* blk_in_w = (const float*)d_in[6];
  const float* blk_conv_w = (const float*)d_in[7];
  const float* blk_decay = (const float*)d_in[8];
  const float* blk_scale = (const float*)d_in[9];
  const float* blk_out_w = (const float*)d_in[10];
  const float* blk_rms_w = (const float*)d_in[11];
  const float* head_w1 = (const float*)d_in[12];
  const float* head_b1 = (const float*)d_in[13];
  const float* head_ln_g = (const float*)d_in[14];
  const float* head_ln_b = (const float*)d_in[15];
  const float* head_w2 = (const float*)d_in[16];
  const float* head_b2 = (const float*)d_in[17];

  char* wsb = (char*)d_ws;
  float* h = (float*)(wsb + 0);                         // 4 MB fp32 [4096][256]
  float* G = (float*)(wsb + (4 << 20));                 // 4 MB fp32 [4096][256]
  unsigned short* hnb = (unsigned short*)(wsb + (8 << 20));    // 2 MB bf16
  unsigned short* xb = (unsigned short*)(wsb + (10 << 20));    // 2 MB bf16
  unsigned short* xpb = (unsigned short*)(wsb + (12 << 20));   // 8 MB bf16 [4096][1024]
  unsigned short* yb = (unsigned short*)(wsb + (20 << 20));    // 4 MB bf16 [4096][512]
  float* pooled = (float*)(wsb + (24 << 20));                  // 8 KB
  unsigned short* inwT = (unsigned short*)(wsb + (25 << 20));  // [256][256]
  unsigned short* binwT = inwT + 65536;                        // 3x [1024][256]
  unsigned short* boutwT = binwT + 786432;                     // 3x [256][512]
  float* out = (float*)d_out;

  k_prep_w<<<dim3(32, 16, 7), 256, 0, stream>>>(in_proj_w, blk_in_w, blk_out_w,
                                                inwT, binwT, boutwT);
  k_cast<<<1024, 256, 0, stream>>>(x, xb);
  // h = LN(x @ in_proj_w)
  k_mfma_gemm<64, 64, 256, false><<<dim3(64, 4), 256, 0, stream>>>(xb, inwT, G, 256);
  k_ln<false><<<1024, 256, 0, stream>>>(G, in_ln_g, in_ln_b, h);
  for (int i = 0; i < 3; ++i) {
    k_ln<true><<<1024, 256, 0, stream>>>(h, norms_g + i * 256, norms_b + i * 256, hnb);
    k_mfma_gemm<64, 128, 256, true><<<dim3(64, 8), 256, 0, stream>>>(
        hnb, binwT + (size_t)i * 262144, xpb, 1024);
    k_scan2<<<dim3(16, 8), 256, 0, stream>>>(xpb, blk_conv_w + i * 1536,
                                             blk_decay + i * 512, blk_scale + i * 512,
                                             yb);
    k_mfma_gemm<64, 64, 512, false><<<dim3(64, 4), 256, 0, stream>>>(
        yb, boutwT + (size_t)i * 131072, G, 256);
    k_rms_res<<<1024, 256, 0, stream>>>(G, blk_rms_w + i * 256, h);
  }
  k_pool<<<8, 256, 0, stream>>>(h, pooled);
  k_head<<<8, 256, 0, stream>>>(pooled, head_w1, head_b1, head_ln_g, head_ln_b,
                                head_w2, head_b2, out);
}

// Round 3
// 140.746 us; speedup vs baseline: 4.9835x; 1.5878x over previous
//
#include <hip/hip_runtime.h>
#include <math.h>

// B=8, L=512, HID=256, LAT=256, INNER=512, NL=3, M=B*L=4096

typedef __attribute__((ext_vector_type(8))) __bf16 bf16x8;
typedef __attribute__((ext_vector_type(4))) float f32x4;

__device__ __forceinline__ unsigned short f2b(float f) {
  unsigned int x = __float_as_uint(f);
  unsigned int r = (x + 0x7fffu + ((x >> 16) & 1u)) >> 16;  // RNE
  return (unsigned short)r;
}
__device__ __forceinline__ float b2f(unsigned short u) {
  return __uint_as_float(((unsigned int)u) << 16);
}

__device__ __forceinline__ void wave_reduce2(float& a, float& b) {
#pragma unroll
  for (int off = 32; off > 0; off >>= 1) {
    a += __shfl_xor(a, off, 64);
    b += __shfl_xor(b, off, 64);
  }
}
__device__ __forceinline__ float wave_reduce1(float a) {
#pragma unroll
  for (int off = 32; off > 0; off >>= 1) a += __shfl_xor(a, off, 64);
  return a;
}

#define GLD16(gsrc, ldst)                                              \
  __builtin_amdgcn_global_load_lds(                                    \
      (const __attribute__((address_space(1))) void*)(gsrc),           \
      (__attribute__((address_space(3))) void*)(ldst), 16, 0, 0)

// ---------------------------------------------------------------------------
// Weight prep: transpose fp32 [R][C] -> bf16 [C][R].
// z=0: in_proj_w 256x256 ; z=1..3: blk_in_w[i] 256x1024 ; z=4..6: blk_out_w[i] 512x256
// ---------------------------------------------------------------------------
__global__ __launch_bounds__(256) void k_prep_w(
    const float* __restrict__ inproj, const float* __restrict__ binw,
    const float* __restrict__ boutw, unsigned short* __restrict__ inwT,
    unsigned short* __restrict__ binwT, unsigned short* __restrict__ boutwT) {
  __shared__ float t[32][33];
  const int z = blockIdx.z;
  const float* src;
  unsigned short* dst;
  int R, Cc;
  if (z == 0) {
    src = inproj; dst = inwT; R = 256; Cc = 256;
  } else if (z <= 3) {
    src = binw + (size_t)(z - 1) * 256 * 1024;
    dst = binwT + (size_t)(z - 1) * 1024 * 256;
    R = 256; Cc = 1024;
  } else {
    src = boutw + (size_t)(z - 4) * 512 * 256;
    dst = boutwT + (size_t)(z - 4) * 256 * 512;
    R = 512; Cc = 256;
  }
  const int bx = blockIdx.x, by = blockIdx.y;
  if (bx * 32 >= Cc || by * 32 >= R) return;
  const int tx = threadIdx.x & 31, ty = threadIdx.x >> 5;  // 32 x 8
#pragma unroll
  for (int j = 0; j < 4; ++j)
    t[ty + j * 8][tx] = src[(size_t)(by * 32 + ty + j * 8) * Cc + bx * 32 + tx];
  __syncthreads();
#pragma unroll
  for (int j = 0; j < 4; ++j)
    dst[(size_t)(bx * 32 + ty + j * 8) * R + by * 32 + tx] = f2b(t[tx][ty + j * 8]);
}

__global__ __launch_bounds__(256) void k_cast(const float* __restrict__ in,
                                              unsigned short* __restrict__ out) {
  const int i = blockIdx.x * 256 + threadIdx.x;
  float4 v = ((const float4*)in)[i];
  ushort4 o;
  o.x = f2b(v.x); o.y = f2b(v.y); o.z = f2b(v.z); o.w = f2b(v.w);
  ((ushort4*)out)[i] = o;
}

// ---------------------------------------------------------------------------
// MFMA GEMM: C[M][ldc] = A[M][KTOT] (bf16) x Bt[N][KTOT]^T (bf16)
// 256 thr = 4 waves 2x2; 16x16x32 fragments; C/D: col=lane&15, row=(lane>>4)*4+reg.
// ---------------------------------------------------------------------------
template <int BM, int BN, int KTOT, bool OBF16>
__global__ __launch_bounds__(256) void k_mfma_gemm(
    const unsigned short* __restrict__ A, const unsigned short* __restrict__ Bt,
    void* __restrict__ C, int ldc) {
  constexpr int WTM = BM / 2, WTN = BN / 2;
  constexpr int FM = WTM / 16, FN = WTN / 16;
  __shared__ unsigned short sA[BM * 32];
  __shared__ unsigned short sB[BN * 32];
  const int tid = threadIdx.x;
  const int lane = tid & 63;
  const int wave = tid >> 6;
  const int wr = wave >> 1, wc = wave & 1;
  const int bm0 = blockIdx.x * BM, bn0 = blockIdx.y * BN;
  const int fr = lane & 15, fg = lane >> 4;
  f32x4 acc[FM][FN] = {};
  for (int kt = 0; kt < KTOT; kt += 32) {
    __syncthreads();
    constexpr int CA = (BM * 4) / 256;
#pragma unroll
    for (int j = 0; j < CA; ++j) {
      int idx = tid + j * 256;
      int row = idx >> 2, slot = idx & 3;
      const unsigned short* src = A + (size_t)(bm0 + row) * KTOT + kt + slot * 8;
      GLD16(src, &sA[idx * 8]);
    }
    constexpr int CB = (BN * 4) / 256;
#pragma unroll
    for (int j = 0; j < CB; ++j) {
      int idx = tid + j * 256;
      int row = idx >> 2, slot = idx & 3;
      const unsigned short* src = Bt + (size_t)(bn0 + row) * KTOT + kt + slot * 8;
      GLD16(src, &sB[idx * 8]);
    }
    __syncthreads();
    bf16x8 af[FM], bf[FN];
#pragma unroll
    for (int m = 0; m < FM; ++m)
      af[m] = *(const bf16x8*)&sA[(wr * WTM + m * 16 + fr) * 32 + fg * 8];
#pragma unroll
    for (int n = 0; n < FN; ++n)
      bf[n] = *(const bf16x8*)&sB[(wc * WTN + n * 16 + fr) * 32 + fg * 8];
#pragma unroll
    for (int m = 0; m < FM; ++m)
#pragma unroll
      for (int n = 0; n < FN; ++n)
        acc[m][n] =
            __builtin_amdgcn_mfma_f32_16x16x32_bf16(af[m], bf[n], acc[m][n], 0, 0, 0);
  }
#pragma unroll
  for (int m = 0; m < FM; ++m)
#pragma unroll
    for (int n = 0; n < FN; ++n)
#pragma unroll
      for (int j = 0; j < 4; ++j) {
        int row = bm0 + wr * WTM + m * 16 + fg * 4 + j;
        int col = bn0 + wc * WTN + n * 16 + fr;
        float v = acc[m][n][j];
        if (OBF16)
          ((unsigned short*)C)[(size_t)row * ldc + col] = f2b(v);
        else
          ((float*)C)[(size_t)row * ldc + col] = v;
      }
}

// ---------------------------------------------------------------------------
// Dual LayerNorm: h = LN1(G); hnb = bf16(LN2(h)). One wave per 256-wide row.
// ---------------------------------------------------------------------------
__global__ __launch_bounds__(256) void k_ln_dual(
    const float* __restrict__ G, const float* __restrict__ g1,
    const float* __restrict__ b1, const float* __restrict__ g2,
    const float* __restrict__ b2, float* __restrict__ h,
    unsigned short* __restrict__ hnb) {
  const int gid = blockIdx.x * 256 + threadIdx.x;
  const int row = gid >> 6, lane = gid & 63, c0 = lane * 4;
  float4 v = *(const float4*)&G[(size_t)row * 256 + c0];
  float s = v.x + v.y + v.z + v.w;
  float sq = v.x * v.x + v.y * v.y + v.z * v.z + v.w * v.w;
  wave_reduce2(s, sq);
  float mu = s * (1.f / 256.f);
  float rstd = rsqrtf(sq * (1.f / 256.f) - mu * mu + 1e-5f);
  float4 gg = *(const float4*)&g1[c0];
  float4 bb = *(const float4*)&b1[c0];
  float4 o;
  o.x = (v.x - mu) * rstd * gg.x + bb.x;
  o.y = (v.y - mu) * rstd * gg.y + bb.y;
  o.z = (v.z - mu) * rstd * gg.z + bb.z;
  o.w = (v.w - mu) * rstd * gg.w + bb.w;
  *(float4*)&h[(size_t)row * 256 + c0] = o;
  // second LN
  float s2 = o.x + o.y + o.z + o.w;
  float q2 = o.x * o.x + o.y * o.y + o.z * o.z + o.w * o.w;
  wave_reduce2(s2, q2);
  float mu2 = s2 * (1.f / 256.f);
  float rs2 = rsqrtf(q2 * (1.f / 256.f) - mu2 * mu2 + 1e-5f);
  float4 g2v = *(const float4*)&g2[c0];
  float4 b2v = *(const float4*)&b2[c0];
  ushort4 u;
  u.x = f2b((o.x - mu2) * rs2 * g2v.x + b2v.x);
  u.y = f2b((o.y - mu2) * rs2 * g2v.y + b2v.y);
  u.z = f2b((o.z - mu2) * rs2 * g2v.z + b2v.z);
  u.w = f2b((o.w - mu2) * rs2 * g2v.w + b2v.w);
  *(ushort4*)&hnb[(size_t)row * 256 + c0] = u;
}

// ---------------------------------------------------------------------------
// h += RMSNorm(G)*rw ; optionally hnb = bf16(LN(h_new)) for the next layer.
// ---------------------------------------------------------------------------
template <bool DO_LN>
__global__ __launch_bounds__(256) void k_rms_res_ln(
    const float* __restrict__ G, const float* __restrict__ rw,
    float* __restrict__ h, const float* __restrict__ g2,
    const float* __restrict__ b2, unsigned short* __restrict__ hnb) {
  const int gid = blockIdx.x * 256 + threadIdx.x;
  const int row = gid >> 6, lane = gid & 63, c0 = lane * 4;
  float4 v = *(const float4*)&G[(size_t)row * 256 + c0];
  float sq = v.x * v.x + v.y * v.y + v.z * v.z + v.w * v.w;
  sq = wave_reduce1(sq);
  float rstd = rsqrtf(sq * (1.f / 256.f) + 1e-6f);
  float4 rr = *(const float4*)&rw[c0];
  float4 hh = *(const float4*)&h[(size_t)row * 256 + c0];
  hh.x += v.x * rstd * rr.x;
  hh.y += v.y * rstd * rr.y;
  hh.z += v.z * rstd * rr.z;
  hh.w += v.w * rstd * rr.w;
  *(float4*)&h[(size_t)row * 256 + c0] = hh;
  if (DO_LN) {
    float s2 = hh.x + hh.y + hh.z + hh.w;
    float q2 = hh.x * hh.x + hh.y * hh.y + hh.z * hh.z + hh.w * hh.w;
    wave_reduce2(s2, q2);
    float mu2 = s2 * (1.f / 256.f);
    float rs2 = rsqrtf(q2 * (1.f / 256.f) - mu2 * mu2 + 1e-5f);
    float4 g2v = *(const float4*)&g2[c0];
    float4 b2v = *(const float4*)&b2[c0];
    ushort4 u;
    u.x = f2b((hh.x - mu2) * rs2 * g2v.x + b2v.x);
    u.y = f2b((hh.y - mu2) * rs2 * g2v.y + b2v.y);
    u.z = f2b((hh.z - mu2) * rs2 * g2v.z + b2v.z);
    u.w = f2b((hh.w - mu2) * rs2 * g2v.w + b2v.w);
    *(ushort4*)&hnb[(size_t)row * 256 + c0] = u;
  }
}

// ---------------------------------------------------------------------------
// Scan: s[t]=a*s[t-1]+coef*conv3(u)[t]; y=s*sigmoid(g).
// Grid (32 d-tiles of 16, 8 b); block 256 = 16 d x 16 chunks of 32 t.
// Pass1: local zero-init scan, s0 stored to LDS. Carry resolve via a^32.
// Pass2 (linearity): s[t] = s0[t] + a^(t+1)*carry; read only the gate.
// ---------------------------------------------------------------------------
__global__ __launch_bounds__(256) void k_scan3(
    const unsigned short* __restrict__ xp, const float* __restrict__ cw,
    const float* __restrict__ decay, const float* __restrict__ scl,
    unsigned short* __restrict__ y) {
  const int b = blockIdx.y;
  const int d0 = blockIdx.x * 16;
  const int ds = threadIdx.x & 15;
  const int ch = threadIdx.x >> 4;
  const int d = d0 + ds;
  const float a = 1.f / (1.f + __expf(-decay[d]));
  const float coef = (1.f - a) * scl[d];
  const float cw0 = cw[d * 3], cw1 = cw[d * 3 + 1], cw2 = cw[d * 3 + 2];
  const int T0 = ch * 32;
  const unsigned short* up = xp + ((size_t)b * 512) * 1024 + d;
  __shared__ float s0[16 * 520];  // ch-plane stride 520 words: <=2-way conflicts
  __shared__ float lend[16][16];
  __shared__ float carry[16][16];
  float* sp = &s0[ch * 520];
  float um1 = T0 >= 1 ? b2f(up[(size_t)(T0 - 1) * 1024]) : 0.f;
  float um2 = T0 >= 2 ? b2f(up[(size_t)(T0 - 2) * 1024]) : 0.f;
  float s = 0.f;
#pragma unroll 8
  for (int t = 0; t < 32; ++t) {
    float u = b2f(up[(size_t)(T0 + t) * 1024]);
    float uc = fmaf(cw0, um2, fmaf(cw1, um1, cw2 * u));
    s = fmaf(a, s, coef * uc);
    sp[t * 16 + ds] = s;
    um2 = um1;
    um1 = u;
  }
  lend[ch][ds] = s;
  __syncthreads();
  if (threadIdx.x < 16) {
    const int dd = d0 + threadIdx.x;
    float aa = 1.f / (1.f + __expf(-decay[dd]));
    float a32 = aa * aa;  // a^2
    a32 = a32 * a32;      // a^4
    a32 = a32 * a32;      // a^8
    a32 = a32 * a32;      // a^16
    a32 = a32 * a32;      // a^32
    float c = 0.f;
#pragma unroll
    for (int j = 0; j < 16; ++j) {
      carry[j][threadIdx.x] = c;
      c = fmaf(a32, c, lend[j][threadIdx.x]);
    }
  }
  __syncthreads();
  const float c = carry[ch][ds];
  const unsigned short* gp = up + 512;
  unsigned short* yp = y + ((size_t)b * 512) * 512 + d;
  float ap = a;
#pragma unroll 8
  for (int t = 0; t < 32; ++t) {
    float gv = b2f(gp[(size_t)(T0 + t) * 1024]);
    float sv = fmaf(ap, c, sp[t * 16 + ds]);
    float sig = 1.f / (1.f + __expf(-gv));
    yp[(size_t)(T0 + t) * 512] = f2b(sv * sig);
    ap *= a;
  }
}

// ---------------------------------------------------------------------------
__global__ __launch_bounds__(256) void k_pool(const float* __restrict__ h,
                                              float* __restrict__ pooled) {
  const int b = blockIdx.x;
  const int c = threadIdx.x;
  float s = 0.f;
#pragma unroll 8
  for (int t = 0; t < 512; ++t) s += h[((size_t)b * 512 + t) * 256 + c];
  float last = h[((size_t)b * 512 + 511) * 256 + c];
  pooled[b * 256 + c] = s * (0.5f / 512.f) + 0.5f * last;
}

// ---------------------------------------------------------------------------
// Head stage 1: z = GELU(LN(pooled@w1+b1)) ; 8 blocks x (256,4), k-split 4.
// ---------------------------------------------------------------------------
__global__ __launch_bounds__(1024) void k_head1(
    const float* __restrict__ pooled, const float* __restrict__ w1,
    const float* __restrict__ b1, const float* __restrict__ lng,
    const float* __restrict__ lnb, float* __restrict__ z) {
  const int b = blockIdx.x;
  const int t = threadIdx.x;   // 0..255
  const int ks = threadIdx.y;  // 0..3
  __shared__ float sp[256];
  __shared__ float part[4][256];
  __shared__ float red[8];
  if (ks == 0) sp[t] = pooled[b * 256 + t];
  __syncthreads();
  float acc = 0.f;
#pragma unroll 8
  for (int k = ks * 64; k < ks * 64 + 64; ++k) acc += sp[k] * w1[(size_t)k * 256 + t];
  part[ks][t] = acc;
  __syncthreads();
  float aval = 0.f;
  if (ks == 0) {
    aval = part[0][t] + part[1][t] + part[2][t] + part[3][t] + b1[t];
    float s = aval, sq = aval * aval;
    wave_reduce2(s, sq);
    const int lane = t & 63, w = t >> 6;
    if (lane == 0) {
      red[w] = s;
      red[4 + w] = sq;
    }
  }
  __syncthreads();
  if (ks == 0) {
    float S = red[0] + red[1] + red[2] + red[3];
    float SQ = red[4] + red[5] + red[6] + red[7];
    float mu = S * (1.f / 256.f);
    float rstd = rsqrtf(SQ * (1.f / 256.f) - mu * mu + 1e-5f);
    float zv = (aval - mu) * rstd * lng[t] + lnb[t];
    zv = 0.5f * zv * (1.f + erff(zv * 0.70710678118654752f));
    z[b * 256 + t] = zv;
  }
}

// ---------------------------------------------------------------------------
// Head stage 2: out = z@w2 + b2 ; 24 blocks x (256,2), k-split 2.
// ---------------------------------------------------------------------------
__global__ __launch_bounds__(512) void k_head2(
    const float* __restrict__ z, const float* __restrict__ w2,
    const float* __restrict__ b2, float* __restrict__ out) {
  const int b = blockIdx.x / 3;
  const int c = (blockIdx.x % 3) * 256 + threadIdx.x;
  const int ks = threadIdx.y;  // 0..1
  __shared__ float sz[256];
  __shared__ float part[256];
  if (ks == 0) sz[threadIdx.x] = z[b * 256 + threadIdx.x];
  __syncthreads();
  float acc = 0.f;
#pragma unroll 8
  for (int k = ks * 128; k < ks * 128 + 128; ++k) acc += sz[k] * w2[(size_t)k * 768 + c];
  if (ks == 1) part[threadIdx.x] = acc;
  __syncthreads();
  if (ks == 0) out[(size_t)b * 768 + c] = acc + part[threadIdx.x] + b2[c];
}

// ---------------------------------------------------------------------------
extern "C" void kernel_launch(void* const* d_in, const int* in_sizes, int n_in,
                              void* d_out, int out_size, void* d_ws, size_t ws_size,
                              hipStream_t stream) {
  const float* x = (const float*)d_in[0];
  const float* in_proj_w = (const float*)d_in[1];
  const float* in_ln_g = (const float*)d_in[2];
  const float* in_ln_b = (const float*)d_in[3];
  const float* norms_g = (const float*)d_in[4];
  const float* norms_b = (const float*)d_in[5];
  const float* blk_in_w = (const float*)d_in[6];
  const float* blk_conv_w = (const float*)d_in[7];
  const float* blk_decay = (const float*)d_in[8];
  const float* blk_scale = (const float*)d_in[9];
  const float* blk_out_w = (const float*)d_in[10];
  const float* blk_rms_w = (const float*)d_in[11];
  const float* head_w1 = (const float*)d_in[12];
  const float* head_b1 = (const float*)d_in[13];
  const float* head_ln_g = (const float*)d_in[14];
  const float* head_ln_b = (const float*)d_in[15];
  const float* head_w2 = (const float*)d_in[16];
  const float* head_b2 = (const float*)d_in[17];

  char* wsb = (char*)d_ws;
  float* h = (float*)(wsb + 0);                                // 4 MB [4096][256]
  float* G = (float*)(wsb + (4 << 20));                        // 4 MB [4096][256]
  unsigned short* hnb = (unsigned short*)(wsb + (8 << 20));    // 2 MB bf16
  unsigned short* xb = (unsigned short*)(wsb + (10 << 20));    // 2 MB bf16
  unsigned short* xpb = (unsigned short*)(wsb + (12 << 20));   // 8 MB bf16 [4096][1024]
  unsigned short* yb = (unsigned short*)(wsb + (20 << 20));    // 4 MB bf16 [4096][512]
  float* pooled = (float*)(wsb + (24 << 20));                  // 8 KB
  float* zbuf = (float*)(wsb + (24 << 20) + 16384);            // 8 KB
  unsigned short* inwT = (unsigned short*)(wsb + (25 << 20));  // [256][256]
  unsigned short* binwT = inwT + 65536;                        // 3x [1024][256]
  unsigned short* boutwT = binwT + 786432;                     // 3x [256][512]
  float* out = (float*)d_out;

  k_prep_w<<<dim3(32, 16, 7), 256, 0, stream>>>(in_proj_w, blk_in_w, blk_out_w,
                                                inwT, binwT, boutwT);
  k_cast<<<1024, 256, 0, stream>>>(x, xb);
  k_mfma_gemm<64, 64, 256, false><<<dim3(64, 4), 256, 0, stream>>>(xb, inwT, G, 256);
  k_ln_dual<<<1024, 256, 0, stream>>>(G, in_ln_g, in_ln_b, norms_g, norms_b, h, hnb);
  for (int i = 0; i < 3; ++i) {
    k_mfma_gemm<64, 128, 256, true><<<dim3(64, 8), 256, 0, stream>>>(
        hnb, binwT + (size_t)i * 262144, xpb, 1024);
    k_scan3<<<dim3(32, 8), 256, 0, stream>>>(xpb, blk_conv_w + i * 1536,
                                             blk_decay + i * 512, blk_scale + i * 512,
                                             yb);
    k_mfma_gemm<64, 64, 512, false><<<dim3(64, 4), 256, 0, stream>>>(
        yb, boutwT + (size_t)i * 131072, G, 256);
    if (i < 2)
      k_rms_res_ln<true><<<1024, 256, 0, stream>>>(
          G, blk_rms_w + i * 256, h, norms_g + (i + 1) * 256, norms_b + (i + 1) * 256,
          hnb);
    else
      k_rms_res_ln<false><<<1024, 256, 0, stream>>>(G, blk_rms_w + i * 256, h,
                                                    nullptr, nullptr, nullptr);
  }
  k_pool<<<8, 256, 0, stream>>>(h, pooled);
  k_head1<<<8, dim3(256, 4), 0, stream>>>(pooled, head_w1, head_b1, head_ln_g,
                                          head_ln_b, zbuf);
  k_head2<<<24, dim3(256, 2), 0, stream>>>(zbuf, head_w2, head_b2, out);
}

// Round 4
// 133.764 us; speedup vs baseline: 5.2436x; 1.0522x over previous
//
#include <hip/hip_runtime.h>
#include <math.h>

// B=8, L=512, HID=256, LAT=256, INNER=512, NL=3, M=B*L=4096

typedef __attribute__((ext_vector_type(8))) __bf16 bf16x8;
typedef __attribute__((ext_vector_type(4))) float f32x4;

__device__ __forceinline__ unsigned short f2b(float f) {
  unsigned int x = __float_as_uint(f);
  unsigned int r = (x + 0x7fffu + ((x >> 16) & 1u)) >> 16;  // RNE
  return (unsigned short)r;
}
__device__ __forceinline__ float b2f(unsigned short u) {
  return __uint_as_float(((unsigned int)u) << 16);
}

__device__ __forceinline__ void wave_reduce2(float& a, float& b) {
#pragma unroll
  for (int off = 32; off > 0; off >>= 1) {
    a += __shfl_xor(a, off, 64);
    b += __shfl_xor(b, off, 64);
  }
}
__device__ __forceinline__ float wave_reduce1(float a) {
#pragma unroll
  for (int off = 32; off > 0; off >>= 1) a += __shfl_xor(a, off, 64);
  return a;
}

#define GLD16(gsrc, ldst)                                              \
  __builtin_amdgcn_global_load_lds(                                    \
      (const __attribute__((address_space(1))) void*)(gsrc),           \
      (__attribute__((address_space(3))) void*)(ldst), 16, 0, 0)

// ---------------------------------------------------------------------------
// Setup: z=0..6 weight transpose fp32 [R][C] -> bf16 [C][R]; z=7 cast x->bf16.
// ---------------------------------------------------------------------------
__global__ __launch_bounds__(256) void k_setup(
    const float* __restrict__ inproj, const float* __restrict__ binw,
    const float* __restrict__ boutw, const float* __restrict__ x,
    unsigned short* __restrict__ inwT, unsigned short* __restrict__ binwT,
    unsigned short* __restrict__ boutwT, unsigned short* __restrict__ xb) {
  const int z = blockIdx.z;
  if (z == 7) {  // cast: 512 blocks x 256 thr x 2 float4
    const int q = blockIdx.y * 32 + blockIdx.x;
#pragma unroll
    for (int j = 0; j < 2; ++j) {
      int i = q * 512 + threadIdx.x + j * 256;
      float4 v = ((const float4*)x)[i];
      ushort4 o;
      o.x = f2b(v.x); o.y = f2b(v.y); o.z = f2b(v.z); o.w = f2b(v.w);
      ((ushort4*)xb)[i] = o;
    }
    return;
  }
  __shared__ float t[32][33];
  const float* src;
  unsigned short* dst;
  int R, Cc;
  if (z == 0) {
    src = inproj; dst = inwT; R = 256; Cc = 256;
  } else if (z <= 3) {
    src = binw + (size_t)(z - 1) * 256 * 1024;
    dst = binwT + (size_t)(z - 1) * 1024 * 256;
    R = 256; Cc = 1024;
  } else {
    src = boutw + (size_t)(z - 4) * 512 * 256;
    dst = boutwT + (size_t)(z - 4) * 256 * 512;
    R = 512; Cc = 256;
  }
  const int bx = blockIdx.x, by = blockIdx.y;
  if (bx * 32 >= Cc || by * 32 >= R) return;
  const int tx = threadIdx.x & 31, ty = threadIdx.x >> 5;
#pragma unroll
  for (int j = 0; j < 4; ++j)
    t[ty + j * 8][tx] = src[(size_t)(by * 32 + ty + j * 8) * Cc + bx * 32 + tx];
  __syncthreads();
#pragma unroll
  for (int j = 0; j < 4; ++j)
    dst[(size_t)(bx * 32 + ty + j * 8) * R + by * 32 + tx] = f2b(t[tx][ty + j * 8]);
}

// ---------------------------------------------------------------------------
// MFMA GEMM (no epilogue): C bf16 = A[M][KTOT] x Bt[N][KTOT]^T ; 128x128 tile.
// ---------------------------------------------------------------------------
template <int KTOT>
__global__ __launch_bounds__(256) void k_mfma_gemm(
    const unsigned short* __restrict__ A, const unsigned short* __restrict__ Bt,
    unsigned short* __restrict__ C, int ldc) {
  constexpr int BM = 128, BN = 128;
  __shared__ unsigned short sA[BM * 32];
  __shared__ unsigned short sB[BN * 32];
  const int tid = threadIdx.x;
  const int lane = tid & 63;
  const int wave = tid >> 6;
  const int wr = wave >> 1, wc = wave & 1;
  const int bm0 = blockIdx.x * BM, bn0 = blockIdx.y * BN;
  const int fr = lane & 15, fg = lane >> 4;
  f32x4 acc[4][4] = {};
  for (int kt = 0; kt < KTOT; kt += 32) {
    __syncthreads();
#pragma unroll
    for (int j = 0; j < 2; ++j) {
      int idx = tid + j * 256;
      int row = idx >> 2, slot = idx & 3;
      GLD16(A + (size_t)(bm0 + row) * KTOT + kt + slot * 8, &sA[idx * 8]);
    }
#pragma unroll
    for (int j = 0; j < 2; ++j) {
      int idx = tid + j * 256;
      int row = idx >> 2, slot = idx & 3;
      GLD16(Bt + (size_t)(bn0 + row) * KTOT + kt + slot * 8, &sB[idx * 8]);
    }
    __syncthreads();
    bf16x8 af[4], bf[4];
#pragma unroll
    for (int m = 0; m < 4; ++m)
      af[m] = *(const bf16x8*)&sA[(wr * 64 + m * 16 + fr) * 32 + fg * 8];
#pragma unroll
    for (int n = 0; n < 4; ++n)
      bf[n] = *(const bf16x8*)&sB[(wc * 64 + n * 16 + fr) * 32 + fg * 8];
#pragma unroll
    for (int m = 0; m < 4; ++m)
#pragma unroll
      for (int n = 0; n < 4; ++n)
        acc[m][n] =
            __builtin_amdgcn_mfma_f32_16x16x32_bf16(af[m], bf[n], acc[m][n], 0, 0, 0);
  }
#pragma unroll
  for (int m = 0; m < 4; ++m)
#pragma unroll
    for (int n = 0; n < 4; ++n)
#pragma unroll
      for (int j = 0; j < 4; ++j) {
        int row = bm0 + wr * 64 + m * 16 + fg * 4 + j;
        int col = bn0 + wc * 64 + n * 16 + fr;
        C[(size_t)row * ldc + col] = f2b(acc[m][n][j]);
      }
}

// ---------------------------------------------------------------------------
// Fused GEMM + row-norm epilogue. BM=16, BN=256 (full row). 4 waves split N.
// MODE 0: h = LN1(P); hnb = bf16(LN2(h))          (GEMM1 + dual LN)
// MODE 1: h += RMS(P)*rw; hnb = bf16(LN(h))       (GEMM3, layers 0..1)
// MODE 2: h += RMS(P)*rw                          (GEMM3, layer 2)
// ---------------------------------------------------------------------------
template <int KTOT, int MODE>
__global__ __launch_bounds__(256) void k_gemm_epi(
    const unsigned short* __restrict__ A, const unsigned short* __restrict__ Bt,
    const float* __restrict__ p1, const float* __restrict__ p2,
    const float* __restrict__ g2, const float* __restrict__ b2,
    float* __restrict__ h, unsigned short* __restrict__ hnb) {
  constexpr int BM = 16;
  __shared__ __align__(16) unsigned char smem[(BM * 32 + 256 * 32) * 2];
  unsigned short* sA = (unsigned short*)smem;
  unsigned short* sB = sA + BM * 32;
  float* ep = (float*)smem;  // [16][260] after K-loop
  const int tid = threadIdx.x;
  const int lane = tid & 63;
  const int wc = tid >> 6;  // wave = N quarter
  const int bm0 = blockIdx.x * BM;
  const int fr = lane & 15, fg = lane >> 4;
  f32x4 acc[4] = {};
  for (int kt = 0; kt < KTOT; kt += 32) {
    __syncthreads();
    if (tid < BM * 4) {
      int row = tid >> 2, slot = tid & 3;
      GLD16(A + (size_t)(bm0 + row) * KTOT + kt + slot * 8, &sA[tid * 8]);
    }
#pragma unroll
    for (int j = 0; j < 4; ++j) {
      int idx = tid + j * 256;
      int row = idx >> 2, slot = idx & 3;
      GLD16(Bt + (size_t)row * KTOT + kt + slot * 8, &sB[idx * 8]);
    }
    __syncthreads();
    bf16x8 af = *(const bf16x8*)&sA[fr * 32 + fg * 8];
    bf16x8 bf[4];
#pragma unroll
    for (int n = 0; n < 4; ++n)
      bf[n] = *(const bf16x8*)&sB[(wc * 64 + n * 16 + fr) * 32 + fg * 8];
#pragma unroll
    for (int n = 0; n < 4; ++n)
      acc[n] = __builtin_amdgcn_mfma_f32_16x16x32_bf16(af, bf[n], acc[n], 0, 0, 0);
  }
  __syncthreads();
#pragma unroll
  for (int n = 0; n < 4; ++n)
#pragma unroll
    for (int j = 0; j < 4; ++j)
      ep[(fg * 4 + j) * 260 + wc * 64 + n * 16 + fr] = acc[n][j];
  __syncthreads();
  // norm phase: wave wc handles rows wc*4 .. wc*4+3 ; lane covers 4 cols
  const int c0 = lane * 4;
  float4 q1 = *(const float4*)&p1[c0];
  float4 q2v = (MODE == 0) ? *(const float4*)&p2[c0] : float4{0, 0, 0, 0};
  float4 gg2 = (MODE != 2) ? *(const float4*)&g2[c0] : float4{0, 0, 0, 0};
  float4 bb2 = (MODE != 2) ? *(const float4*)&b2[c0] : float4{0, 0, 0, 0};
#pragma unroll
  for (int r = 0; r < 4; ++r) {
    const int row = wc * 4 + r;
    const size_t grow = (size_t)(bm0 + row) * 256 + c0;
    float4 v = *(const float4*)&ep[row * 260 + c0];
    float4 hh;
    if (MODE == 0) {
      float s = v.x + v.y + v.z + v.w;
      float sq = v.x * v.x + v.y * v.y + v.z * v.z + v.w * v.w;
      wave_reduce2(s, sq);
      float mu = s * (1.f / 256.f);
      float rstd = rsqrtf(sq * (1.f / 256.f) - mu * mu + 1e-5f);
      hh.x = (v.x - mu) * rstd * q1.x + q2v.x;
      hh.y = (v.y - mu) * rstd * q1.y + q2v.y;
      hh.z = (v.z - mu) * rstd * q1.z + q2v.z;
      hh.w = (v.w - mu) * rstd * q1.w + q2v.w;
      *(float4*)&h[grow] = hh;
    } else {
      float sq = v.x * v.x + v.y * v.y + v.z * v.z + v.w * v.w;
      sq = wave_reduce1(sq);
      float rstd = rsqrtf(sq * (1.f / 256.f) + 1e-6f);
      hh = *(const float4*)&h[grow];
      hh.x += v.x * rstd * q1.x;
      hh.y += v.y * rstd * q1.y;
      hh.z += v.z * rstd * q1.z;
      hh.w += v.w * rstd * q1.w;
      *(float4*)&h[grow] = hh;
    }
    if (MODE != 2) {
      float s2 = hh.x + hh.y + hh.z + hh.w;
      float sq2 = hh.x * hh.x + hh.y * hh.y + hh.z * hh.z + hh.w * hh.w;
      wave_reduce2(s2, sq2);
      float mu2 = s2 * (1.f / 256.f);
      float rs2 = rsqrtf(sq2 * (1.f / 256.f) - mu2 * mu2 + 1e-5f);
      ushort4 u;
      u.x = f2b((hh.x - mu2) * rs2 * gg2.x + bb2.x);
      u.y = f2b((hh.y - mu2) * rs2 * gg2.y + bb2.y);
      u.z = f2b((hh.z - mu2) * rs2 * gg2.z + bb2.z);
      u.w = f2b((hh.w - mu2) * rs2 * gg2.w + bb2.w);
      *(ushort4*)&hnb[grow] = u;
    }
  }
}

// ---------------------------------------------------------------------------
// Scan: s[t]=a*s[t-1]+coef*conv3(u)[t]; y=s*sigmoid(g). s0 kept in REGISTERS.
// Grid (32 d-tiles of 16, 8 b); block 256 = 16 d x 16 chunks of 32 t.
// Linearity: s[t] = s0[t] + a^(t+1)*carry.
// ---------------------------------------------------------------------------
__global__ __launch_bounds__(256) void k_scan4(
    const unsigned short* __restrict__ xp, const float* __restrict__ cw,
    const float* __restrict__ decay, const float* __restrict__ scl,
    unsigned short* __restrict__ y) {
  const int b = blockIdx.y;
  const int d0 = blockIdx.x * 16;
  const int ds = threadIdx.x & 15;
  const int ch = threadIdx.x >> 4;
  const int d = d0 + ds;
  const float a = 1.f / (1.f + __expf(-decay[d]));
  const float coef = (1.f - a) * scl[d];
  const float cw0 = cw[d * 3], cw1 = cw[d * 3 + 1], cw2 = cw[d * 3 + 2];
  const int T0 = ch * 32;
  const unsigned short* up = xp + ((size_t)b * 512) * 1024 + d;
  __shared__ float lend[16][16];
  __shared__ float carry[16][16];
  float s0r[32];
  float um1 = T0 >= 1 ? b2f(up[(size_t)(T0 - 1) * 1024]) : 0.f;
  float um2 = T0 >= 2 ? b2f(up[(size_t)(T0 - 2) * 1024]) : 0.f;
  float s = 0.f;
#pragma unroll
  for (int t = 0; t < 32; ++t) {
    float u = b2f(up[(size_t)(T0 + t) * 1024]);
    float uc = fmaf(cw0, um2, fmaf(cw1, um1, cw2 * u));
    s = fmaf(a, s, coef * uc);
    s0r[t] = s;
    um2 = um1;
    um1 = u;
  }
  lend[ch][ds] = s;
  __syncthreads();
  if (threadIdx.x < 16) {
    const int dd = d0 + threadIdx.x;
    float aa = 1.f / (1.f + __expf(-decay[dd]));
    float a32 = aa * aa;
    a32 = a32 * a32;
    a32 = a32 * a32;
    a32 = a32 * a32;
    a32 = a32 * a32;  // a^32
    float c = 0.f;
#pragma unroll
    for (int j = 0; j < 16; ++j) {
      carry[j][threadIdx.x] = c;
      c = fmaf(a32, c, lend[j][threadIdx.x]);
    }
  }
  __syncthreads();
  const float c = carry[ch][ds];
  const unsigned short* gp = up + 512;
  unsigned short* yp = y + ((size_t)b * 512) * 512 + d;
  float ap = a;
#pragma unroll
  for (int t = 0; t < 32; ++t) {
    float gv = b2f(gp[(size_t)(T0 + t) * 1024]);
    float sv = fmaf(ap, c, s0r[t]);
    float sig = 1.f / (1.f + __expf(-gv));
    yp[(size_t)(T0 + t) * 512] = f2b(sv * sig);
    ap *= a;
  }
}

// ---------------------------------------------------------------------------
// Pool partials: part[b][chk][c] = sum over 64 t-rows. Grid (8 b, 8 chk).
// ---------------------------------------------------------------------------
__global__ __launch_bounds__(256) void k_pool_part(const float* __restrict__ h,
                                                   float* __restrict__ part) {
  const int b = blockIdx.x, chk = blockIdx.y, c = threadIdx.x;
  float s = 0.f;
  const float* base = h + (((size_t)b * 512) + chk * 64) * 256 + c;
#pragma unroll 8
  for (int t = 0; t < 64; ++t) s += base[(size_t)t * 256];
  part[((size_t)b * 8 + chk) * 256 + c] = s;
}

// ---------------------------------------------------------------------------
// Fused head: pooled -> GEMV1 -> LN -> GELU -> GEMV2 -> out. 8 blocks x (256,4).
// ---------------------------------------------------------------------------
__global__ __launch_bounds__(1024) void k_head(
    const float* __restrict__ part, const float* __restrict__ h,
    const float* __restrict__ w1, const float* __restrict__ b1,
    const float* __restrict__ lng, const float* __restrict__ lnb,
    const float* __restrict__ w2, const float* __restrict__ b2,
    float* __restrict__ out) {
  const int b = blockIdx.x;
  const int t = threadIdx.x;
  const int ks = threadIdx.y;
  __shared__ float sp[256];
  __shared__ float sz[256];
  __shared__ float part4[4][256];
  __shared__ float red[8];
  if (ks == 0) {
    float s = 0.f;
#pragma unroll
    for (int j = 0; j < 8; ++j) s += part[((size_t)b * 8 + j) * 256 + t];
    sp[t] = s * (0.5f / 512.f) + 0.5f * h[(((size_t)b * 512) + 511) * 256 + t];
  }
  __syncthreads();
  float acc = 0.f;
#pragma unroll 8
  for (int k = ks * 64; k < ks * 64 + 64; ++k) acc += sp[k] * w1[(size_t)k * 256 + t];
  part4[ks][t] = acc;
  __syncthreads();
  if (ks == 0) {
    float aval = part4[0][t] + part4[1][t] + part4[2][t] + part4[3][t] + b1[t];
    float s = aval, sq = aval * aval;
    wave_reduce2(s, sq);
    const int lane = t & 63, w = t >> 6;
    if (lane == 0) {
      red[w] = s;
      red[4 + w] = sq;
    }
    part4[0][t] = aval;  // stash
  }
  __syncthreads();
  if (ks == 0) {
    float S = red[0] + red[1] + red[2] + red[3];
    float SQ = red[4] + red[5] + red[6] + red[7];
    float mu = S * (1.f / 256.f);
    float rstd = rsqrtf(SQ * (1.f / 256.f) - mu * mu + 1e-5f);
    float zv = (part4[0][t] - mu) * rstd * lng[t] + lnb[t];
    zv = 0.5f * zv * (1.f + erff(zv * 0.70710678118654752f));
    sz[t] = zv;
  }
  __syncthreads();
  const int col = ks * 256 + t;
  if (col < 768) {
    float a = b2[col];
#pragma unroll 8
    for (int k = 0; k < 256; ++k) a += sz[k] * w2[(size_t)k * 768 + col];
    out[(size_t)b * 768 + col] = a;
  }
}

// ---------------------------------------------------------------------------
extern "C" void kernel_launch(void* const* d_in, const int* in_sizes, int n_in,
                              void* d_out, int out_size, void* d_ws, size_t ws_size,
                              hipStream_t stream) {
  const float* x = (const float*)d_in[0];
  const float* in_proj_w = (const float*)d_in[1];
  const float* in_ln_g = (const float*)d_in[2];
  const float* in_ln_b = (const float*)d_in[3];
  const float* norms_g = (const float*)d_in[4];
  const float* norms_b = (const float*)d_in[5];
  const float* blk_in_w = (const float*)d_in[6];
  const float* blk_conv_w = (const float*)d_in[7];
  const float* blk_decay = (const float*)d_in[8];
  const float* blk_scale = (const float*)d_in[9];
  const float* blk_out_w = (const float*)d_in[10];
  const float* blk_rms_w = (const float*)d_in[11];
  const float* head_w1 = (const float*)d_in[12];
  const float* head_b1 = (const float*)d_in[13];
  const float* head_ln_g = (const float*)d_in[14];
  const float* head_ln_b = (const float*)d_in[15];
  const float* head_w2 = (const float*)d_in[16];
  const float* head_b2 = (const float*)d_in[17];

  char* wsb = (char*)d_ws;
  float* h = (float*)(wsb + 0);                                // 4 MB [4096][256]
  float* part = (float*)(wsb + (4 << 20));                     // 64 KB [8][8][256]
  unsigned short* hnb = (unsigned short*)(wsb + (8 << 20));    // 2 MB bf16
  unsigned short* xb = (unsigned short*)(wsb + (10 << 20));    // 2 MB bf16
  unsigned short* xpb = (unsigned short*)(wsb + (12 << 20));   // 8 MB bf16 [4096][1024]
  unsigned short* yb = (unsigned short*)(wsb + (20 << 20));    // 4 MB bf16 [4096][512]
  unsigned short* inwT = (unsigned short*)(wsb + (25 << 20));  // [256][256]
  unsigned short* binwT = inwT + 65536;                        // 3x [1024][256]
  unsigned short* boutwT = binwT + 786432;                     // 3x [256][512]
  float* out = (float*)d_out;

  k_setup<<<dim3(32, 16, 8), 256, 0, stream>>>(in_proj_w, blk_in_w, blk_out_w, x,
                                               inwT, binwT, boutwT, xb);
  // h = LN1(x @ in_proj_w); hnb = bf16(LN2(h))
  k_gemm_epi<256, 0><<<256, 256, 0, stream>>>(xb, inwT, in_ln_g, in_ln_b, norms_g,
                                              norms_b, h, hnb);
  for (int i = 0; i < 3; ++i) {
    k_mfma_gemm<256><<<dim3(32, 8), 256, 0, stream>>>(
        hnb, binwT + (size_t)i * 262144, xpb, 1024);
    k_scan4<<<dim3(32, 8), 256, 0, stream>>>(xpb, blk_conv_w + i * 1536,
                                             blk_decay + i * 512, blk_scale + i * 512,
                                             yb);
    if (i < 2)
      k_gemm_epi<512, 1><<<256, 256, 0, stream>>>(
          yb, boutwT + (size_t)i * 131072, blk_rms_w + i * 256, nullptr,
          norms_g + (i + 1) * 256, norms_b + (i + 1) * 256, h, hnb);
    else
      k_gemm_epi<512, 2><<<256, 256, 0, stream>>>(
          yb, boutwT + (size_t)i * 131072, blk_rms_w + i * 256, nullptr, nullptr,
          nullptr, h, nullptr);
  }
  k_pool_part<<<dim3(8, 8), 256, 0, stream>>>(h, part);
  k_head<<<8, dim3(256, 4), 0, stream>>>(part, h, head_w1, head_b1, head_ln_g,
                                         head_ln_b, head_w2, head_b2, out);
}

// Round 5
// 112.885 us; speedup vs baseline: 6.2135x; 1.1850x over previous
//
#include <hip/hip_runtime.h>
#include <math.h>

// B=8, L=512, HID=256, LAT=256, INNER=512, NL=3, M=B*L=4096

typedef __attribute__((ext_vector_type(8))) __bf16 bf16x8;
typedef __attribute__((ext_vector_type(4))) float f32x4;

__device__ __forceinline__ unsigned short f2b(float f) {
  unsigned int x = __float_as_uint(f);
  unsigned int r = (x + 0x7fffu + ((x >> 16) & 1u)) >> 16;  // RNE
  return (unsigned short)r;
}
__device__ __forceinline__ float b2f(unsigned short u) {
  return __uint_as_float(((unsigned int)u) << 16);
}

__device__ __forceinline__ void wave_reduce2(float& a, float& b) {
#pragma unroll
  for (int off = 32; off > 0; off >>= 1) {
    a += __shfl_xor(a, off, 64);
    b += __shfl_xor(b, off, 64);
  }
}
__device__ __forceinline__ float wave_reduce1(float a) {
#pragma unroll
  for (int off = 32; off > 0; off >>= 1) a += __shfl_xor(a, off, 64);
  return a;
}

#define GLD16(gsrc, ldst)                                              \
  __builtin_amdgcn_global_load_lds(                                    \
      (const __attribute__((address_space(1))) void*)(gsrc),           \
      (__attribute__((address_space(3))) void*)(ldst), 16, 0, 0)

// ---------------------------------------------------------------------------
// Setup: z=0..6 weight transpose fp32 [R][C] -> bf16 [C][R]; z=7 cast x->bf16.
// ---------------------------------------------------------------------------
__global__ __launch_bounds__(256) void k_setup(
    const float* __restrict__ inproj, const float* __restrict__ binw,
    const float* __restrict__ boutw, const float* __restrict__ x,
    unsigned short* __restrict__ inwT, unsigned short* __restrict__ binwT,
    unsigned short* __restrict__ boutwT, unsigned short* __restrict__ xb) {
  const int z = blockIdx.z;
  if (z == 7) {  // cast: 512 blocks x 256 thr x 2 float4
    const int q = blockIdx.y * 32 + blockIdx.x;
#pragma unroll
    for (int j = 0; j < 2; ++j) {
      int i = q * 512 + threadIdx.x + j * 256;
      float4 v = ((const float4*)x)[i];
      ushort4 o;
      o.x = f2b(v.x); o.y = f2b(v.y); o.z = f2b(v.z); o.w = f2b(v.w);
      ((ushort4*)xb)[i] = o;
    }
    return;
  }
  __shared__ float t[32][33];
  const float* src;
  unsigned short* dst;
  int R, Cc;
  if (z == 0) {
    src = inproj; dst = inwT; R = 256; Cc = 256;
  } else if (z <= 3) {
    src = binw + (size_t)(z - 1) * 256 * 1024;
    dst = binwT + (size_t)(z - 1) * 1024 * 256;
    R = 256; Cc = 1024;
  } else {
    src = boutw + (size_t)(z - 4) * 512 * 256;
    dst = boutwT + (size_t)(z - 4) * 256 * 512;
    R = 512; Cc = 256;
  }
  const int bx = blockIdx.x, by = blockIdx.y;
  if (bx * 32 >= Cc || by * 32 >= R) return;
  const int tx = threadIdx.x & 31, ty = threadIdx.x >> 5;
#pragma unroll
  for (int j = 0; j < 4; ++j)
    t[ty + j * 8][tx] = src[(size_t)(by * 32 + ty + j * 8) * Cc + bx * 32 + tx];
  __syncthreads();
#pragma unroll
  for (int j = 0; j < 4; ++j)
    dst[(size_t)(bx * 32 + ty + j * 8) * R + by * 32 + tx] = f2b(t[tx][ty + j * 8]);
}

// ---------------------------------------------------------------------------
// Fused GEMM2 + conv3 + decay-scan + gate.
// Block = (16-channel tile, batch). Computes xp columns [d0..d0+16) (=u) and
// [512+d0..512+d0+16) (=g) for ALL 512 rows of the batch in MFMA accumulators
// (4 waves x 128 rows), redistributes u,g through LDS planes, then runs the
// chunked scan (16 ds x 16 chunks of 32 t) and writes gated y bf16.
// K-loop is 2-phase pipelined (STAGE next buf before compute, 1 barrier/phase).
// ---------------------------------------------------------------------------
__global__ __launch_bounds__(256) void k_gemm2_scan(
    const unsigned short* __restrict__ A,   // hnb [4096][256]
    const unsigned short* __restrict__ Bt,  // binwT layer base [1024][256]
    const float* __restrict__ cw, const float* __restrict__ decay,
    const float* __restrict__ scl, unsigned short* __restrict__ y) {
  __shared__ unsigned short sA[2][512 * 32];  // 64 KB (dbuf A-tile [512][32])
  __shared__ unsigned short sB[2][32 * 32];   // 4 KB  (dbuf B-tile [32][32])
  __shared__ float su[16 * 520];              // 32.5 KB u planes
  __shared__ float sg[16 * 520];              // 32.5 KB g planes
  __shared__ float lend[16][16];
  __shared__ float carry[16][16];
  const int b = blockIdx.y;
  const int d0 = blockIdx.x * 16;
  const int tid = threadIdx.x;
  const int lane = tid & 63;
  const int w = tid >> 6;
  const int fr = lane & 15, fg = lane >> 4;
  const unsigned short* Ab = A + (size_t)b * 512 * 256;

#define STAGE2(buf, kt)                                                     \
  {                                                                         \
    for (int j = 0; j < 8; ++j) {                                           \
      int idx = tid + j * 256;                                              \
      int row = idx >> 2, slot = idx & 3;                                   \
      GLD16(Ab + (size_t)row * 256 + (kt) + slot * 8, &sA[buf][idx * 8]);   \
    }                                                                       \
    if (tid < 128) {                                                        \
      int row = tid >> 2, slot = tid & 3;                                   \
      int gr = row < 16 ? d0 + row : 496 + d0 + row;                        \
      GLD16(Bt + (size_t)gr * 256 + (kt) + slot * 8, &sB[buf][tid * 8]);    \
    }                                                                       \
  }

  f32x4 au[8] = {}, ag[8] = {};
  STAGE2(0, 0);
  __syncthreads();
#pragma unroll
  for (int ph = 0; ph < 8; ++ph) {
    const int cur = ph & 1;
    if (ph < 7) STAGE2(cur ^ 1, (ph + 1) * 32);
    bf16x8 bu = *(const bf16x8*)&sB[cur][fr * 32 + fg * 8];
    bf16x8 bg = *(const bf16x8*)&sB[cur][(16 + fr) * 32 + fg * 8];
#pragma unroll
    for (int m = 0; m < 8; ++m) {
      bf16x8 af = *(const bf16x8*)&sA[cur][(w * 128 + m * 16 + fr) * 32 + fg * 8];
      au[m] = __builtin_amdgcn_mfma_f32_16x16x32_bf16(af, bu, au[m], 0, 0, 0);
      ag[m] = __builtin_amdgcn_mfma_f32_16x16x32_bf16(af, bg, ag[m], 0, 0, 0);
    }
    __syncthreads();
  }
#undef STAGE2
  // scatter accumulators -> LDS planes: row = w*128+m*16+fg*4+j, channel fr
#pragma unroll
  for (int m = 0; m < 8; ++m)
#pragma unroll
    for (int j = 0; j < 4; ++j) {
      int row = w * 128 + m * 16 + fg * 4 + j;
      int off = (row >> 5) * 520 + (row & 31) * 16 + fr;
      su[off] = au[m][j];
      sg[off] = ag[m][j];
    }
  __syncthreads();
  // scan: thread = (ds, ch); chunk ch covers t in [ch*32, ch*32+32)
  const int ds = tid & 15, ch = tid >> 4;
  const int d = d0 + ds;
  const float a = 1.f / (1.f + __expf(-decay[d]));
  const float coef = (1.f - a) * scl[d];
  const float cw0 = cw[d * 3], cw1 = cw[d * 3 + 1], cw2 = cw[d * 3 + 2];
  const int T0 = ch * 32;
  float um1 = T0 >= 1 ? su[((T0 - 1) >> 5) * 520 + ((T0 - 1) & 31) * 16 + ds] : 0.f;
  float um2 = T0 >= 2 ? su[((T0 - 2) >> 5) * 520 + ((T0 - 2) & 31) * 16 + ds] : 0.f;
  float s = 0.f, s0r[32];
#pragma unroll
  for (int t = 0; t < 32; ++t) {
    float u = su[ch * 520 + t * 16 + ds];
    float uc = fmaf(cw0, um2, fmaf(cw1, um1, cw2 * u));
    s = fmaf(a, s, coef * uc);
    s0r[t] = s;
    um2 = um1;
    um1 = u;
  }
  lend[ch][ds] = s;
  __syncthreads();
  if (tid < 16) {
    float aa = 1.f / (1.f + __expf(-decay[d0 + tid]));
    float a32 = aa * aa;
    a32 = a32 * a32;
    a32 = a32 * a32;
    a32 = a32 * a32;
    a32 = a32 * a32;  // a^32
    float c = 0.f;
#pragma unroll
    for (int j = 0; j < 16; ++j) {
      carry[j][tid] = c;
      c = fmaf(a32, c, lend[j][tid]);
    }
  }
  __syncthreads();
  const float c = carry[ch][ds];
  unsigned short* yp = y + ((size_t)b * 512 + T0) * 512 + d;
  float ap = a;
#pragma unroll
  for (int t = 0; t < 32; ++t) {
    float gv = sg[ch * 520 + t * 16 + ds];
    float sv = fmaf(ap, c, s0r[t]);
    float sig = 1.f / (1.f + __expf(-gv));
    yp[(size_t)t * 512] = f2b(sv * sig);
    ap *= a;
  }
}

// ---------------------------------------------------------------------------
// Fused GEMM + row-norm epilogue, 2-phase pipelined. BM=16, BN=256 full row.
// MODE 0: h = LN1(P)+; hnb = bf16(LN2(h))         (GEMM1 + dual LN)
// MODE 1: h += RMS(P)*rw; hnb = bf16(LN(h))       (GEMM3, layers 0..1)
// MODE 2: h += RMS(P)*rw; part[blk] = colsum(h16) (GEMM3, layer 2 + pool)
// ---------------------------------------------------------------------------
template <int KTOT, int MODE>
__global__ __launch_bounds__(256) void k_gemm_epi(
    const unsigned short* __restrict__ A, const unsigned short* __restrict__ Bt,
    const float* __restrict__ p1, const float* __restrict__ p2,
    const float* __restrict__ g2, const float* __restrict__ b2,
    float* __restrict__ h, unsigned short* __restrict__ hnb,
    float* __restrict__ part) {
  constexpr int NP = KTOT / 32;
  __shared__ __align__(16) unsigned char smem[(2 * (16 * 32 + 256 * 32)) * 2];
  __shared__ float ppart[4][256];
  unsigned short* sA0 = (unsigned short*)smem;  // [2][16*32]
  unsigned short* sB0 = sA0 + 2 * 16 * 32;      // [2][256*32]
  float* ep = (float*)smem;                     // [16][260] overlay after loop
  const int tid = threadIdx.x;
  const int lane = tid & 63;
  const int wc = tid >> 6;
  const int bm0 = blockIdx.x * 16;
  const int fr = lane & 15, fg = lane >> 4;

#define STAGEE(buf, kt)                                                     \
  {                                                                         \
    if (tid < 64) {                                                         \
      int row = tid >> 2, slot = tid & 3;                                   \
      GLD16(A + (size_t)(bm0 + row) * KTOT + (kt) + slot * 8,               \
            &sA0[(buf) * 512 + tid * 8]);                                   \
    }                                                                       \
    for (int j = 0; j < 4; ++j) {                                           \
      int idx = tid + j * 256;                                              \
      int row = idx >> 2, slot = idx & 3;                                   \
      GLD16(Bt + (size_t)row * KTOT + (kt) + slot * 8,                      \
            &sB0[(buf) * 8192 + idx * 8]);                                  \
    }                                                                       \
  }

  f32x4 acc[4] = {};
  STAGEE(0, 0);
  __syncthreads();
#pragma unroll
  for (int ph = 0; ph < NP; ++ph) {
    const int cur = ph & 1;
    if (ph < NP - 1) STAGEE(cur ^ 1, (ph + 1) * 32);
    bf16x8 af = *(const bf16x8*)&sA0[cur * 512 + fr * 32 + fg * 8];
    bf16x8 bf[4];
#pragma unroll
    for (int n = 0; n < 4; ++n)
      bf[n] = *(const bf16x8*)&sB0[cur * 8192 + (wc * 64 + n * 16 + fr) * 32 + fg * 8];
#pragma unroll
    for (int n = 0; n < 4; ++n)
      acc[n] = __builtin_amdgcn_mfma_f32_16x16x32_bf16(af, bf[n], acc[n], 0, 0, 0);
    __syncthreads();
  }
#undef STAGEE
#pragma unroll
  for (int n = 0; n < 4; ++n)
#pragma unroll
    for (int j = 0; j < 4; ++j)
      ep[(fg * 4 + j) * 260 + wc * 64 + n * 16 + fr] = acc[n][j];
  __syncthreads();
  // norm phase: wave wc handles rows wc*4..wc*4+3 ; lane covers 4 cols
  const int c0 = lane * 4;
  float4 q1 = *(const float4*)&p1[c0];
  float4 q2v = (MODE == 0) ? *(const float4*)&p2[c0] : float4{0, 0, 0, 0};
  float4 gg2 = (MODE != 2) ? *(const float4*)&g2[c0] : float4{0, 0, 0, 0};
  float4 bb2 = (MODE != 2) ? *(const float4*)&b2[c0] : float4{0, 0, 0, 0};
  float4 psum = {0.f, 0.f, 0.f, 0.f};
#pragma unroll
  for (int r = 0; r < 4; ++r) {
    const int row = wc * 4 + r;
    const size_t grow = (size_t)(bm0 + row) * 256 + c0;
    float4 v = *(const float4*)&ep[row * 260 + c0];
    float4 hh;
    if (MODE == 0) {
      float s = v.x + v.y + v.z + v.w;
      float sq = v.x * v.x + v.y * v.y + v.z * v.z + v.w * v.w;
      wave_reduce2(s, sq);
      float mu = s * (1.f / 256.f);
      float rstd = rsqrtf(sq * (1.f / 256.f) - mu * mu + 1e-5f);
      hh.x = (v.x - mu) * rstd * q1.x + q2v.x;
      hh.y = (v.y - mu) * rstd * q1.y + q2v.y;
      hh.z = (v.z - mu) * rstd * q1.z + q2v.z;
      hh.w = (v.w - mu) * rstd * q1.w + q2v.w;
      *(float4*)&h[grow] = hh;
    } else {
      float sq = v.x * v.x + v.y * v.y + v.z * v.z + v.w * v.w;
      sq = wave_reduce1(sq);
      float rstd = rsqrtf(sq * (1.f / 256.f) + 1e-6f);
      hh = *(const float4*)&h[grow];
      hh.x += v.x * rstd * q1.x;
      hh.y += v.y * rstd * q1.y;
      hh.z += v.z * rstd * q1.z;
      hh.w += v.w * rstd * q1.w;
      *(float4*)&h[grow] = hh;
    }
    if (MODE != 2) {
      float s2 = hh.x + hh.y + hh.z + hh.w;
      float sq2 = hh.x * hh.x + hh.y * hh.y + hh.z * hh.z + hh.w * hh.w;
      wave_reduce2(s2, sq2);
      float mu2 = s2 * (1.f / 256.f);
      float rs2 = rsqrtf(sq2 * (1.f / 256.f) - mu2 * mu2 + 1e-5f);
      ushort4 u;
      u.x = f2b((hh.x - mu2) * rs2 * gg2.x + bb2.x);
      u.y = f2b((hh.y - mu2) * rs2 * gg2.y + bb2.y);
      u.z = f2b((hh.z - mu2) * rs2 * gg2.z + bb2.z);
      u.w = f2b((hh.w - mu2) * rs2 * gg2.w + bb2.w);
      *(ushort4*)&hnb[grow] = u;
    } else {
      psum.x += hh.x;
      psum.y += hh.y;
      psum.z += hh.z;
      psum.w += hh.w;
    }
  }
  if (MODE == 2) {  // per-block column partial sums for the pool
    *(float4*)&ppart[wc][c0] = psum;
    __syncthreads();
    float pv = ppart[0][tid] + ppart[1][tid] + ppart[2][tid] + ppart[3][tid];
    part[(size_t)blockIdx.x * 256 + tid] = pv;
  }
}

// ---------------------------------------------------------------------------
// Fused head: pool-finish -> GEMV1 -> LN -> GELU -> GEMV2. 8 blocks x (256,4).
// part layout: [256 blocks][256 cols]; batch b owns blocks b*32..b*32+31.
// ---------------------------------------------------------------------------
__global__ __launch_bounds__(1024) void k_head(
    const float* __restrict__ part, const float* __restrict__ h,
    const float* __restrict__ w1, const float* __restrict__ b1,
    const float* __restrict__ lng, const float* __restrict__ lnb,
    const float* __restrict__ w2, const float* __restrict__ b2,
    float* __restrict__ out) {
  const int b = blockIdx.x;
  const int t = threadIdx.x;
  const int ks = threadIdx.y;
  __shared__ float sp[256];
  __shared__ float sz[256];
  __shared__ float part4[4][256];
  __shared__ float red[8];
  if (ks == 0) {
    float s = 0.f;
#pragma unroll
    for (int j = 0; j < 32; ++j) s += part[((size_t)b * 32 + j) * 256 + t];
    sp[t] = s * (0.5f / 512.f) + 0.5f * h[(((size_t)b * 512) + 511) * 256 + t];
  }
  __syncthreads();
  float acc = 0.f;
#pragma unroll 8
  for (int k = ks * 64; k < ks * 64 + 64; ++k) acc += sp[k] * w1[(size_t)k * 256 + t];
  part4[ks][t] = acc;
  __syncthreads();
  if (ks == 0) {
    float aval = part4[0][t] + part4[1][t] + part4[2][t] + part4[3][t] + b1[t];
    float s = aval, sq = aval * aval;
    wave_reduce2(s, sq);
    const int lane = t & 63, w = t >> 6;
    if (lane == 0) {
      red[w] = s;
      red[4 + w] = sq;
    }
    part4[0][t] = aval;  // stash
  }
  __syncthreads();
  if (ks == 0) {
    float S = red[0] + red[1] + red[2] + red[3];
    float SQ = red[4] + red[5] + red[6] + red[7];
    float mu = S * (1.f / 256.f);
    float rstd = rsqrtf(SQ * (1.f / 256.f) - mu * mu + 1e-5f);
    float zv = (part4[0][t] - mu) * rstd * lng[t] + lnb[t];
    zv = 0.5f * zv * (1.f + erff(zv * 0.70710678118654752f));
    sz[t] = zv;
  }
  __syncthreads();
  const int col = ks * 256 + t;
  if (col < 768) {
    float a = b2[col];
#pragma unroll 8
    for (int k = 0; k < 256; ++k) a += sz[k] * w2[(size_t)k * 768 + col];
    out[(size_t)b * 768 + col] = a;
  }
}

// ---------------------------------------------------------------------------
extern "C" void kernel_launch(void* const* d_in, const int* in_sizes, int n_in,
                              void* d_out, int out_size, void* d_ws, size_t ws_size,
                              hipStream_t stream) {
  const float* x = (const float*)d_in[0];
  const float* in_proj_w = (const float*)d_in[1];
  const float* in_ln_g = (const float*)d_in[2];
  const float* in_ln_b = (const float*)d_in[3];
  const float* norms_g = (const float*)d_in[4];
  const float* norms_b = (const float*)d_in[5];
  const float* blk_in_w = (const float*)d_in[6];
  const float* blk_conv_w = (const float*)d_in[7];
  const float* blk_decay = (const float*)d_in[8];
  const float* blk_scale = (const float*)d_in[9];
  const float* blk_out_w = (const float*)d_in[10];
  const float* blk_rms_w = (const float*)d_in[11];
  const float* head_w1 = (const float*)d_in[12];
  const float* head_b1 = (const float*)d_in[13];
  const float* head_ln_g = (const float*)d_in[14];
  const float* head_ln_b = (const float*)d_in[15];
  const float* head_w2 = (const float*)d_in[16];
  const float* head_b2 = (const float*)d_in[17];

  char* wsb = (char*)d_ws;
  float* h = (float*)(wsb + 0);                                // 4 MB [4096][256]
  float* part = (float*)(wsb + (4 << 20));                     // 256 KB [256][256]
  unsigned short* hnb = (unsigned short*)(wsb + (8 << 20));    // 2 MB bf16
  unsigned short* xb = (unsigned short*)(wsb + (10 << 20));    // 2 MB bf16
  unsigned short* yb = (unsigned short*)(wsb + (12 << 20));    // 4 MB bf16 [4096][512]
  unsigned short* inwT = (unsigned short*)(wsb + (25 << 20));  // [256][256]
  unsigned short* binwT = inwT + 65536;                        // 3x [1024][256]
  unsigned short* boutwT = binwT + 786432;                     // 3x [256][512]
  float* out = (float*)d_out;

  k_setup<<<dim3(32, 16, 8), 256, 0, stream>>>(in_proj_w, blk_in_w, blk_out_w, x,
                                               inwT, binwT, boutwT, xb);
  // h = LN1(x @ in_proj_w); hnb = bf16(LN2(h))
  k_gemm_epi<256, 0><<<256, 256, 0, stream>>>(xb, inwT, in_ln_g, in_ln_b, norms_g,
                                              norms_b, h, hnb, nullptr);
  for (int i = 0; i < 3; ++i) {
    k_gemm2_scan<<<dim3(32, 8), 256, 0, stream>>>(
        hnb, binwT + (size_t)i * 262144, blk_conv_w + i * 1536, blk_decay + i * 512,
        blk_scale + i * 512, yb);
    if (i < 2)
      k_gemm_epi<512, 1><<<256, 256, 0, stream>>>(
          yb, boutwT + (size_t)i * 131072, blk_rms_w + i * 256, nullptr,
          norms_g + (i + 1) * 256, norms_b + (i + 1) * 256, h, hnb, nullptr);
    else
      k_gemm_epi<512, 2><<<256, 256, 0, stream>>>(
          yb, boutwT + (size_t)i * 131072, blk_rms_w + i * 256, nullptr, nullptr,
          nullptr, h, nullptr, part);
  }
  k_head<<<8, dim3(256, 4), 0, stream>>>(part, h, head_w1, head_b1, head_ln_g,
                                         head_ln_b, head_w2, head_b2, out);
}

// Round 6
// 98.296 us; speedup vs baseline: 7.1357x; 1.1484x over previous
//
#include <hip/hip_runtime.h>
#include <math.h>

// B=8, L=512, HID=256, LAT=256, INNER=512, NL=3, M=B*L=4096

typedef __attribute__((ext_vector_type(8))) __bf16 bf16x8;
typedef __attribute__((ext_vector_type(4))) float f32x4;

__device__ __forceinline__ unsigned short f2b(float f) {
  unsigned int x = __float_as_uint(f);
  unsigned int r = (x + 0x7fffu + ((x >> 16) & 1u)) >> 16;  // RNE
  return (unsigned short)r;
}
__device__ __forceinline__ float b2f(unsigned short u) {
  return __uint_as_float(((unsigned int)u) << 16);
}

__device__ __forceinline__ void wave_reduce2(float& a, float& b) {
#pragma unroll
  for (int off = 32; off > 0; off >>= 1) {
    a += __shfl_xor(a, off, 64);
    b += __shfl_xor(b, off, 64);
  }
}
__device__ __forceinline__ float wave_reduce1(float a) {
#pragma unroll
  for (int off = 32; off > 0; off >>= 1) a += __shfl_xor(a, off, 64);
  return a;
}

__device__ __forceinline__ bf16x8 cvt8(float4 a, float4 b) {
  bf16x8 r;
  r[0] = (__bf16)a.x; r[1] = (__bf16)a.y; r[2] = (__bf16)a.z; r[3] = (__bf16)a.w;
  r[4] = (__bf16)b.x; r[5] = (__bf16)b.y; r[6] = (__bf16)b.z; r[7] = (__bf16)b.w;
  return r;
}

#define GLD16(gsrc, ldst)                                              \
  __builtin_amdgcn_global_load_lds(                                    \
      (const __attribute__((address_space(1))) void*)(gsrc),           \
      (__attribute__((address_space(3))) void*)(ldst), 16, 0, 0)

// ---------------------------------------------------------------------------
// Setup: z=0..6 weight transpose fp32 [R][C] -> bf16 [C][R].
// ---------------------------------------------------------------------------
__global__ __launch_bounds__(256) void k_setup(
    const float* __restrict__ inproj, const float* __restrict__ binw,
    const float* __restrict__ boutw, unsigned short* __restrict__ inwT,
    unsigned short* __restrict__ binwT, unsigned short* __restrict__ boutwT) {
  __shared__ float t[32][33];
  const int z = blockIdx.z;
  const float* src;
  unsigned short* dst;
  int R, Cc;
  if (z == 0) {
    src = inproj; dst = inwT; R = 256; Cc = 256;
  } else if (z <= 3) {
    src = binw + (size_t)(z - 1) * 256 * 1024;
    dst = binwT + (size_t)(z - 1) * 1024 * 256;
    R = 256; Cc = 1024;
  } else {
    src = boutw + (size_t)(z - 4) * 512 * 256;
    dst = boutwT + (size_t)(z - 4) * 256 * 512;
    R = 512; Cc = 256;
  }
  const int bx = blockIdx.x, by = blockIdx.y;
  if (bx * 32 >= Cc || by * 32 >= R) return;
  const int tx = threadIdx.x & 31, ty = threadIdx.x >> 5;
#pragma unroll
  for (int j = 0; j < 4; ++j)
    t[ty + j * 8][tx] = src[(size_t)(by * 32 + ty + j * 8) * Cc + bx * 32 + tx];
  __syncthreads();
#pragma unroll
  for (int j = 0; j < 4; ++j)
    dst[(size_t)(bx * 32 + ty + j * 8) * R + by * 32 + tx] = f2b(t[tx][ty + j * 8]);
}

// ---------------------------------------------------------------------------
// Fused GEMM + row-norm epilogue. BM=16, BN=256 full row, KTOT in chunks of
// 128 (A-chunk + B-chunk double-buffered, XOR-swizzled slots, prefetch issued
// AFTER the barrier so it overlaps compute).
// MODE 0: h = LN1(P); hnb = bf16(LN2(h))   (A = x fp32, GEMM1 + dual LN)
// MODE 1: h += RMS(P)*rw; hnb = bf16(LN(h))
// MODE 2: h += RMS(P)*rw; part[blk] = colsum
// ---------------------------------------------------------------------------
template <int KTOT, int MODE, bool AF32>
__global__ __launch_bounds__(256) void k_gemm_epi(
    const void* __restrict__ A, const unsigned short* __restrict__ Bt,
    const float* __restrict__ p1, const float* __restrict__ p2,
    const float* __restrict__ g2, const float* __restrict__ b2,
    float* __restrict__ h, unsigned short* __restrict__ hnb,
    float* __restrict__ part) {
  constexpr int NCH = KTOT / 128;
  constexpr int ABYTES = AF32 ? 8192 : 4096;  // 16 rows x 128 k
  __shared__ __align__(16) unsigned char smem[2 * ABYTES + 2 * 65536];
  __shared__ float ppart[4][256];
  unsigned char* sAb = smem;                  // [2][ABYTES]
  unsigned char* sBb = smem + 2 * ABYTES;     // [2][64 KB] 256 rows x 128 k
  float* ep = (float*)smem;                   // [16][260] overlay after loop
  const float* Af = (const float*)A;
  const unsigned short* Ab = (const unsigned short*)A;
  const int tid = threadIdx.x;
  const int lane = tid & 63;
  const int wc = tid >> 6;
  const int bm0 = blockIdx.x * 16;
  const int fr = lane & 15, fg = lane >> 4;

  auto stage = [&](int buf, int c) {
    if (AF32) {  // A fp32: 512 slots (row=idx>>5, 32 slots/row)
#pragma unroll
      for (int j = 0; j < 2; ++j) {
        int idx = tid + j * 256;
        int row = idx >> 5, p = idx & 31, l = p ^ (row & 7);
        GLD16(Af + (size_t)(bm0 + row) * KTOT + c * 128 + l * 4,
              sAb + buf * ABYTES + idx * 16);
      }
    } else {  // A bf16: 256 slots (16 slots/row)
      int row = tid >> 4, p = tid & 15, l = p ^ (row & 7);
      GLD16(Ab + (size_t)(bm0 + row) * KTOT + c * 128 + l * 8,
            sAb + buf * ABYTES + tid * 16);
    }
    // B: 4096 slots (256 rows x 16 slots)
#pragma unroll
    for (int j = 0; j < 16; ++j) {
      int idx = tid + j * 256;
      int row = idx >> 4, p = idx & 15, l = p ^ (row & 7);
      GLD16(Bt + (size_t)row * KTOT + c * 128 + l * 8, sBb + buf * 65536 + idx * 16);
    }
  };

  f32x4 acc[4] = {};
  stage(0, 0);
  for (int c = 0; c < NCH; ++c) {
    const int cur = c & 1;
    __syncthreads();                       // drain chunk c, sync compute c-1
    if (c + 1 < NCH) stage(cur ^ 1, c + 1);  // prefetch overlaps compute
#pragma unroll
    for (int kk = 0; kk < 128; kk += 32) {
      bf16x8 af;
      if (AF32) {
        int l0 = (kk >> 2) + fg * 2;
        int p0 = l0 ^ (fr & 7), p1 = (l0 + 1) ^ (fr & 7);
        const float* base = (const float*)(sAb + cur * ABYTES) + fr * 128;
        float4 v0 = *(const float4*)(base + p0 * 4);
        float4 v1 = *(const float4*)(base + p1 * 4);
        af = cvt8(v0, v1);
      } else {
        int p = ((kk >> 3) + fg) ^ (fr & 7);
        af = *(const bf16x8*)((const unsigned short*)(sAb + cur * ABYTES) + fr * 128 +
                              p * 8);
      }
      int pb = ((kk >> 3) + fg) ^ (fr & 7);
#pragma unroll
      for (int n = 0; n < 4; ++n) {
        const unsigned short* bp = (const unsigned short*)(sBb + cur * 65536) +
                                   (wc * 64 + n * 16 + fr) * 128 + pb * 8;
        acc[n] = __builtin_amdgcn_mfma_f32_16x16x32_bf16(af, *(const bf16x8*)bp,
                                                         acc[n], 0, 0, 0);
      }
    }
  }
  __syncthreads();  // all waves done reading sA/sB before ep overlay
#pragma unroll
  for (int n = 0; n < 4; ++n)
#pragma unroll
    for (int j = 0; j < 4; ++j)
      ep[(fg * 4 + j) * 260 + wc * 64 + n * 16 + fr] = acc[n][j];
  __syncthreads();
  // norm phase: wave wc handles rows wc*4..wc*4+3 ; lane covers 4 cols
  const int c0 = lane * 4;
  float4 q1 = *(const float4*)&p1[c0];
  float4 q2v = (MODE == 0) ? *(const float4*)&p2[c0] : float4{0, 0, 0, 0};
  float4 gg2 = (MODE != 2) ? *(const float4*)&g2[c0] : float4{0, 0, 0, 0};
  float4 bb2 = (MODE != 2) ? *(const float4*)&b2[c0] : float4{0, 0, 0, 0};
  float4 psum = {0.f, 0.f, 0.f, 0.f};
#pragma unroll
  for (int r = 0; r < 4; ++r) {
    const int row = wc * 4 + r;
    const size_t grow = (size_t)(bm0 + row) * 256 + c0;
    float4 v = *(const float4*)&ep[row * 260 + c0];
    float4 hh;
    if (MODE == 0) {
      float s = v.x + v.y + v.z + v.w;
      float sq = v.x * v.x + v.y * v.y + v.z * v.z + v.w * v.w;
      wave_reduce2(s, sq);
      float mu = s * (1.f / 256.f);
      float rstd = rsqrtf(sq * (1.f / 256.f) - mu * mu + 1e-5f);
      hh.x = (v.x - mu) * rstd * q1.x + q2v.x;
      hh.y = (v.y - mu) * rstd * q1.y + q2v.y;
      hh.z = (v.z - mu) * rstd * q1.z + q2v.z;
      hh.w = (v.w - mu) * rstd * q1.w + q2v.w;
      *(float4*)&h[grow] = hh;
    } else {
      float sq = v.x * v.x + v.y * v.y + v.z * v.z + v.w * v.w;
      sq = wave_reduce1(sq);
      float rstd = rsqrtf(sq * (1.f / 256.f) + 1e-6f);
      hh = *(const float4*)&h[grow];
      hh.x += v.x * rstd * q1.x;
      hh.y += v.y * rstd * q1.y;
      hh.z += v.z * rstd * q1.z;
      hh.w += v.w * rstd * q1.w;
      *(float4*)&h[grow] = hh;
    }
    if (MODE != 2) {
      float s2 = hh.x + hh.y + hh.z + hh.w;
      float sq2 = hh.x * hh.x + hh.y * hh.y + hh.z * hh.z + hh.w * hh.w;
      wave_reduce2(s2, sq2);
      float mu2 = s2 * (1.f / 256.f);
      float rs2 = rsqrtf(sq2 * (1.f / 256.f) - mu2 * mu2 + 1e-5f);
      ushort4 u;
      u.x = f2b((hh.x - mu2) * rs2 * gg2.x + bb2.x);
      u.y = f2b((hh.y - mu2) * rs2 * gg2.y + bb2.y);
      u.z = f2b((hh.z - mu2) * rs2 * gg2.z + bb2.z);
      u.w = f2b((hh.w - mu2) * rs2 * gg2.w + bb2.w);
      *(ushort4*)&hnb[grow] = u;
    } else {
      psum.x += hh.x;
      psum.y += hh.y;
      psum.z += hh.z;
      psum.w += hh.w;
    }
  }
  if (MODE == 2) {
    *(float4*)&ppart[wc][c0] = psum;
    __syncthreads();
    float pv = ppart[0][tid] + ppart[1][tid] + ppart[2][tid] + ppart[3][tid];
    part[(size_t)blockIdx.x * 256 + tid] = pv;
  }
}

// ---------------------------------------------------------------------------
// Fused GEMM2 + conv3 + decay-scan + gate. Block = (16-ch tile d0, batch b).
// B-slice (u,g weight rows, 16 KB) staged once; A (batch slab 512x256) staged
// in four 64 KB k-quarters, double-buffered, prefetch after barrier.
// Scan planes overlay the dead quarter buffers.
// ---------------------------------------------------------------------------
__global__ __launch_bounds__(256) void k_gemm2_scan(
    const unsigned short* __restrict__ A,   // hnb [4096][256]
    const unsigned short* __restrict__ Bt,  // binwT layer base [1024][256]
    const float* __restrict__ cw, const float* __restrict__ decay,
    const float* __restrict__ scl, unsigned short* __restrict__ y) {
  __shared__ __align__(16) unsigned char smem[16384 + 2 * 65536];
  unsigned short* sB = (unsigned short*)smem;  // [32][256] shorts, swizzled
  unsigned char* qb = smem + 16384;            // [2][64 KB]: 512 rows x 64 k
  float* su = (float*)(smem + 16384);          // overlay: 16 planes x 520
  float* sg = su + 8320;
  float* lend = sg + 8320;   // [16][16]
  float* carry = lend + 256; // [16][16]
  const int b = blockIdx.y;
  const int d0 = blockIdx.x * 16;
  const int tid = threadIdx.x;
  const int lane = tid & 63;
  const int w = tid >> 6;
  const int fr = lane & 15, fg = lane >> 4;
  const unsigned short* Abp = A + (size_t)b * 512 * 256;

  auto stageQ = [&](int buf, int q) {
#pragma unroll
    for (int j = 0; j < 16; ++j) {
      int idx = tid + j * 256;
      int row = idx >> 3, p = idx & 7, l = p ^ (row & 7);
      GLD16(Abp + (size_t)row * 256 + q * 64 + l * 8, qb + buf * 65536 + idx * 16);
    }
  };
  // stage B once (32 rows x 32 slots)
#pragma unroll
  for (int j = 0; j < 4; ++j) {
    int idx = tid + j * 256;
    int row = idx >> 5, p = idx & 31, l = p ^ (row & 7);
    int gr = row < 16 ? d0 + row : 496 + d0 + row;
    GLD16(Bt + (size_t)gr * 256 + l * 8, smem + idx * 16);
  }
  stageQ(0, 0);

  f32x4 au[8] = {}, ag[8] = {};
#pragma unroll
  for (int q = 0; q < 4; ++q) {
    const int cq = q & 1;
    __syncthreads();                       // drain quarter q (+B on q=0)
    if (q < 3) stageQ(cq ^ 1, q + 1);      // prefetch overlaps compute
#pragma unroll
    for (int kk = 0; kk < 64; kk += 32) {
      int lb = q * 8 + (kk >> 3) + fg;
      int pb = lb ^ (fr & 7);
      bf16x8 bu = *(const bf16x8*)&sB[fr * 256 + pb * 8];
      bf16x8 bg = *(const bf16x8*)&sB[(16 + fr) * 256 + pb * 8];
      int pa = ((kk >> 3) + fg) ^ (fr & 7);
#pragma unroll
      for (int m = 0; m < 8; ++m) {
        int row = w * 128 + m * 16 + fr;
        bf16x8 af =
            *(const bf16x8*)((const unsigned short*)(qb + cq * 65536) + row * 64 +
                             pa * 8);
        au[m] = __builtin_amdgcn_mfma_f32_16x16x32_bf16(af, bu, au[m], 0, 0, 0);
        ag[m] = __builtin_amdgcn_mfma_f32_16x16x32_bf16(af, bg, ag[m], 0, 0, 0);
      }
    }
  }
  __syncthreads();  // all qbuf reads done before scan-plane overlay
  // scatter accumulators -> planes: row = w*128+m*16+fg*4+j, channel fr
#pragma unroll
  for (int m = 0; m < 8; ++m)
#pragma unroll
    for (int j = 0; j < 4; ++j) {
      int row = w * 128 + m * 16 + fg * 4 + j;
      int off = (row >> 5) * 520 + (row & 31) * 16 + fr;
      su[off] = au[m][j];
      sg[off] = ag[m][j];
    }
  __syncthreads();
  // scan: thread = (ds, ch); chunk ch covers t in [ch*32, ch*32+32)
  const int ds = tid & 15, ch = tid >> 4;
  const int d = d0 + ds;
  const float a = 1.f / (1.f + __expf(-decay[d]));
  const float coef = (1.f - a) * scl[d];
  const float cw0 = cw[d * 3], cw1 = cw[d * 3 + 1], cw2 = cw[d * 3 + 2];
  const int T0 = ch * 32;
  float um1 = T0 >= 1 ? su[((T0 - 1) >> 5) * 520 + ((T0 - 1) & 31) * 16 + ds] : 0.f;
  float um2 = T0 >= 2 ? su[((T0 - 2) >> 5) * 520 + ((T0 - 2) & 31) * 16 + ds] : 0.f;
  float s = 0.f, s0r[32];
#pragma unroll
  for (int t = 0; t < 32; ++t) {
    float u = su[ch * 520 + t * 16 + ds];
    float uc = fmaf(cw0, um2, fmaf(cw1, um1, cw2 * u));
    s = fmaf(a, s, coef * uc);
    s0r[t] = s;
    um2 = um1;
    um1 = u;
  }
  lend[ch * 16 + ds] = s;
  __syncthreads();
  if (tid < 16) {
    float aa = 1.f / (1.f + __expf(-decay[d0 + tid]));
    float a32 = aa * aa;
    a32 = a32 * a32;
    a32 = a32 * a32;
    a32 = a32 * a32;
    a32 = a32 * a32;  // a^32
    float c = 0.f;
#pragma unroll
    for (int j = 0; j < 16; ++j) {
      carry[j * 16 + tid] = c;
      c = fmaf(a32, c, lend[j * 16 + tid]);
    }
  }
  __syncthreads();
  const float c = carry[ch * 16 + ds];
  unsigned short* yp = y + ((size_t)b * 512 + T0) * 512 + d;
  float ap = a;
#pragma unroll
  for (int t = 0; t < 32; ++t) {
    float gv = sg[ch * 520 + t * 16 + ds];
    float sv = fmaf(ap, c, s0r[t]);
    float sig = 1.f / (1.f + __expf(-gv));
    yp[(size_t)t * 512] = f2b(sv * sig);
    ap *= a;
  }
}

// ---------------------------------------------------------------------------
// Fused head: pool-finish -> GEMV1 -> LN -> GELU -> GEMV2. 8 blocks x (256,4).
// part layout: [256 blocks][256 cols]; batch b owns blocks b*32..b*32+31.
// ---------------------------------------------------------------------------
__global__ __launch_bounds__(1024) void k_head(
    const float* __restrict__ part, const float* __restrict__ h,
    const float* __restrict__ w1, const float* __restrict__ b1,
    const float* __restrict__ lng, const float* __restrict__ lnb,
    const float* __restrict__ w2, const float* __restrict__ b2,
    float* __restrict__ out) {
  const int b = blockIdx.x;
  const int t = threadIdx.x;
  const int ks = threadIdx.y;
  __shared__ float sp[256];
  __shared__ float sz[256];
  __shared__ float part4[4][256];
  __shared__ float red[8];
  if (ks == 0) {
    float s = 0.f;
#pragma unroll
    for (int j = 0; j < 32; ++j) s += part[((size_t)b * 32 + j) * 256 + t];
    sp[t] = s * (0.5f / 512.f) + 0.5f * h[(((size_t)b * 512) + 511) * 256 + t];
  }
  __syncthreads();
  float acc = 0.f;
#pragma unroll 8
  for (int k = ks * 64; k < ks * 64 + 64; ++k) acc += sp[k] * w1[(size_t)k * 256 + t];
  part4[ks][t] = acc;
  __syncthreads();
  if (ks == 0) {
    float aval = part4[0][t] + part4[1][t] + part4[2][t] + part4[3][t] + b1[t];
    float s = aval, sq = aval * aval;
    wave_reduce2(s, sq);
    const int lane = t & 63, w = t >> 6;
    if (lane == 0) {
      red[w] = s;
      red[4 + w] = sq;
    }
    part4[0][t] = aval;  // stash
  }
  __syncthreads();
  if (ks == 0) {
    float S = red[0] + red[1] + red[2] + red[3];
    float SQ = red[4] + red[5] + red[6] + red[7];
    float mu = S * (1.f / 256.f);
    float rstd = rsqrtf(SQ * (1.f / 256.f) - mu * mu + 1e-5f);
    float zv = (part4[0][t] - mu) * rstd * lng[t] + lnb[t];
    zv = 0.5f * zv * (1.f + erff(zv * 0.70710678118654752f));
    sz[t] = zv;
  }
  __syncthreads();
  const int col = ks * 256 + t;
  if (col < 768) {
    float a = b2[col];
#pragma unroll 8
    for (int k = 0; k < 256; ++k) a += sz[k] * w2[(size_t)k * 768 + col];
    out[(size_t)b * 768 + col] = a;
  }
}

// ---------------------------------------------------------------------------
extern "C" void kernel_launch(void* const* d_in, const int* in_sizes, int n_in,
                              void* d_out, int out_size, void* d_ws, size_t ws_size,
                              hipStream_t stream) {
  const float* x = (const float*)d_in[0];
  const float* in_proj_w = (const float*)d_in[1];
  const float* in_ln_g = (const float*)d_in[2];
  const float* in_ln_b = (const float*)d_in[3];
  const float* norms_g = (const float*)d_in[4];
  const float* norms_b = (const float*)d_in[5];
  const float* blk_in_w = (const float*)d_in[6];
  const float* blk_conv_w = (const float*)d_in[7];
  const float* blk_decay = (const float*)d_in[8];
  const float* blk_scale = (const float*)d_in[9];
  const float* blk_out_w = (const float*)d_in[10];
  const float* blk_rms_w = (const float*)d_in[11];
  const float* head_w1 = (const float*)d_in[12];
  const float* head_b1 = (const float*)d_in[13];
  const float* head_ln_g = (const float*)d_in[14];
  const float* head_ln_b = (const float*)d_in[15];
  const float* head_w2 = (const float*)d_in[16];
  const float* head_b2 = (const float*)d_in[17];

  char* wsb = (char*)d_ws;
  float* h = (float*)(wsb + 0);                                // 4 MB [4096][256]
  float* part = (float*)(wsb + (4 << 20));                     // 256 KB [256][256]
  unsigned short* hnb = (unsigned short*)(wsb + (8 << 20));    // 2 MB bf16
  unsigned short* yb = (unsigned short*)(wsb + (12 << 20));    // 4 MB bf16 [4096][512]
  unsigned short* inwT = (unsigned short*)(wsb + (25 << 20));  // [256][256]
  unsigned short* binwT = inwT + 65536;                        // 3x [1024][256]
  unsigned short* boutwT = binwT + 786432;                     // 3x [256][512]
  float* out = (float*)d_out;

  k_setup<<<dim3(32, 16, 7), 256, 0, stream>>>(in_proj_w, blk_in_w, blk_out_w, inwT,
                                               binwT, boutwT);
  // h = LN1(x @ in_proj_w); hnb = bf16(LN2(h))  (A = x fp32 direct)
  k_gemm_epi<256, 0, true><<<256, 256, 0, stream>>>(
      x, inwT, in_ln_g, in_ln_b, norms_g, norms_b, h, hnb, nullptr);
  for (int i = 0; i < 3; ++i) {
    k_gemm2_scan<<<dim3(32, 8), 256, 0, stream>>>(
        hnb, binwT + (size_t)i * 262144, blk_conv_w + i * 1536, blk_decay + i * 512,
        blk_scale + i * 512, yb);
    if (i < 2)
      k_gemm_epi<512, 1, false><<<256, 256, 0, stream>>>(
          yb, boutwT + (size_t)i * 131072, blk_rms_w + i * 256, nullptr,
          norms_g + (i + 1) * 256, norms_b + (i + 1) * 256, h, hnb, nullptr);
    else
      k_gemm_epi<512, 2, false><<<256, 256, 0, stream>>>(
          yb, boutwT + (size_t)i * 131072, blk_rms_w + i * 256, nullptr, nullptr,
          nullptr, h, nullptr, part);
  }
  k_head<<<8, dim3(256, 4), 0, stream>>>(part, h, head_w1, head_b1, head_ln_g,
                                         head_ln_b, head_w2, head_b2, out);
}